// Round 5
// baseline (245.441 us; speedup 1.0000x reference)
//
#include <hip/hip_runtime.h>
#include <hip/hip_bf16.h>
#include <math.h>

#define EPSV 1e-6f
#define LAMBDAV 1e-3f
#define LN_2PI 1.8378770664093453f

__device__ __forceinline__ float bflo(unsigned int u) {
    union { unsigned int i; float f; } x; x.i = u << 16; return x.f;
}
__device__ __forceinline__ float bfhi(unsigned int u) {
    union { unsigned int i; float f; } x; x.i = u & 0xffff0000u; return x.f;
}
__device__ __forceinline__ unsigned short f2bf(float f) {
    __hip_bfloat16 h = __float2bfloat16(f);
    return *(unsigned short*)&h;
}

typedef __attribute__((ext_vector_type(8))) short s8v;
typedef __attribute__((ext_vector_type(4))) float f4v;
typedef __attribute__((ext_vector_type(2))) int i2v;

// DPP lane-permute move (VALU-latency cross-lane, no LDS pipe).
template<int CTRL>
__device__ __forceinline__ float dpp_mv(float x) {
    return __int_as_float(__builtin_amdgcn_update_dpp(
        0, __float_as_int(x), CTRL, 0xF, 0xF, true));
}
__device__ __forceinline__ float x16_sum(float x) {
#if __has_builtin(__builtin_amdgcn_permlane16_swap)
    i2v r = __builtin_amdgcn_permlane16_swap(__float_as_int(x), __float_as_int(x), false, false);
    return __int_as_float(r.x) + __int_as_float(r.y);
#else
    return x + __int_as_float(__builtin_amdgcn_ds_swizzle(__float_as_int(x), 0x401F));
#endif
}
__device__ __forceinline__ float x16_max(float x) {
#if __has_builtin(__builtin_amdgcn_permlane16_swap)
    i2v r = __builtin_amdgcn_permlane16_swap(__float_as_int(x), __float_as_int(x), false, false);
    return fmaxf(__int_as_float(r.x), __int_as_float(r.y));
#else
    return fmaxf(x, __int_as_float(__builtin_amdgcn_ds_swizzle(__float_as_int(x), 0x401F)));
#endif
}
__device__ __forceinline__ float xhalf_sum(float x) {
#if __has_builtin(__builtin_amdgcn_permlane32_swap)
    i2v r = __builtin_amdgcn_permlane32_swap(__float_as_int(x), __float_as_int(x), false, false);
    return __int_as_float(r.x) + __int_as_float(r.y);
#else
    return x + __shfl_xor(x, 32, 64);
#endif
}
__device__ __forceinline__ float red_max32(float x) {
    x = fmaxf(x, dpp_mv<0xB1>(x));    // quad_perm [1,0,3,2]  (xor 1)
    x = fmaxf(x, dpp_mv<0x4E>(x));    // quad_perm [2,3,0,1]  (xor 2)
    x = fmaxf(x, dpp_mv<0x124>(x));   // row_ror:4
    x = fmaxf(x, dpp_mv<0x128>(x));   // row_ror:8
    return x16_max(x);
}
__device__ __forceinline__ float red_sum32(float x) {
    x += dpp_mv<0xB1>(x);
    x += dpp_mv<0x4E>(x);
    x += dpp_mv<0x124>(x);
    x += dpp_mv<0x128>(x);
    return x16_sum(x);
}
__device__ __forceinline__ float red_sum16(float x) {
    x += dpp_mv<0xB1>(x);
    x += dpp_mv<0x4E>(x);
    x += dpp_mv<0x124>(x);
    x += dpp_mv<0x128>(x);
    return x;
}
__device__ __forceinline__ void expand8(const uint4 u, float* va) {
    va[0] = bflo(u.x); va[1] = bfhi(u.x);
    va[2] = bflo(u.y); va[3] = bfhi(u.y);
    va[4] = bflo(u.z); va[5] = bfhi(u.z);
    va[6] = bflo(u.w); va[7] = bfhi(u.w);
}

// Kernel 1: MFMA conv, M-split: 576 blocks = (i2, cq-half). 30KB LDS/block ->
// ~5 blocks/CU capacity, removes the 288=256+32 two-round quantization.
__global__ __launch_bounds__(256)
void conv_v_kernel(const float* __restrict__ x, const float* __restrict__ w,
                   __hip_bfloat16* __restrict__ vout)
{
    __shared__ unsigned short wb[256 * 40];  // [cq_local][p pad40]
    __shared__ unsigned short pb[128 * 40];  // [n][p pad40]

    const int bid = blockIdx.x;
    const int i2  = bid >> 1;
    const int mh  = bid & 1;                 // cq half: [mh*256, mh*256+256)
    const int tid = threadIdx.x;

    // zero k=16..31 padding (mfma reads k<32)
    for (int u = tid; u < 256 * 8; u += 256) {
        int r = u >> 3, j = u & 7;
        *(unsigned int*)&wb[r * 40 + 16 + j * 2] = 0;
    }
    for (int u = tid; u < 128 * 8; u += 256) {
        int r = u >> 3, j = u & 7;
        *(unsigned int*)&pb[r * 40 + 16 + j * 2] = 0;
    }
    // stage w[i2][c][p][q] fp32 -> wb[(c_local*16+q)][p] bf16 for c_local 0..15
    #pragma unroll 4
    for (int u = 0; u < 16; ++u) {
        int idx = u * 256 + tid;               // cl*256 + p*16 + q
        int cl = idx >> 8, p = (idx >> 4) & 15, q = idx & 15;
        wb[(cl * 16 + q) * 40 + p] = f2bf(w[(size_t)i2 * 8192 + mh * 4096 + idx]);
    }
    // fused gather: pb[nn][p] from x via reference reshape scramble
    #pragma unroll
    for (int u = 0; u < 8; ++u) {
        int idx = u * 256 + tid;               // nn*16 + p
        int nn = idx >> 4, p = idx & 15;
        int e  = i2 * 16 + p;
        int k2 = e >> 9, c2 = e & 511;
        int f  = k2 * 544 + c2;
        int ci = f / 9, kk = f - ci * 9;
        int bi = nn >> 6, oi = (nn >> 3) & 7, oj = nn & 7;
        int row = 2 * oi + kk / 3 - 1;
        int col = 2 * oj + (kk - (kk / 3) * 3) - 1;
        float val = 0.f;
        if ((unsigned)row < 16u && (unsigned)col < 16u)
            val = x[((bi * 16 + row) * 16 + col) * 544 + ci];
        pb[nn * 40 + p] = f2bf(val);
    }
    __syncthreads();

    const int lane = tid & 63;
    const int wv   = tid >> 6;
    const int l16  = lane & 15;
    const int quad = lane >> 4;
    const int cq0l = wv * 64;                  // local cq base of this wave

    s8v afrag[4], bfrag[8];
    #pragma unroll
    for (int mt = 0; mt < 4; ++mt)
        afrag[mt] = *(const s8v*)&wb[(cq0l + mt * 16 + l16) * 40 + quad * 8];
    #pragma unroll
    for (int nt = 0; nt < 8; ++nt)
        bfrag[nt] = *(const s8v*)&pb[(nt * 16 + l16) * 40 + quad * 8];

    #pragma unroll
    for (int nt = 0; nt < 8; ++nt) {
        const int nl = nt * 16 + l16;
        #pragma unroll
        for (int mt = 0; mt < 4; ++mt) {
            f4v acc = {0.f, 0.f, 0.f, 0.f};
            acc = __builtin_amdgcn_mfma_f32_16x16x32_bf16(afrag[mt], bfrag[nt], acc, 0, 0, 0);
            int cq = mh * 256 + cq0l + mt * 16 + quad * 4;
            unsigned int lo = f2bf(acc[0]) | ((unsigned int)f2bf(acc[1]) << 16);
            unsigned int hi = f2bf(acc[2]) | ((unsigned int)f2bf(acc[3]) << 16);
            uint2 pk; pk.x = lo; pk.y = hi;
            *(uint2*)((unsigned short*)vout + ((size_t)nl * 288 + i2) * 512 + cq) = pk;
        }
    }
}

// Kernel 2: EM routing. R2/R4 structure (one block per n, 16 waves, lane =
// (qh,c), VALU-pipe cross-lane) + 4-row ILP: each wave processes 4 rows per
// iteration (4 independent softmax chains interleaved) to fill the ~170-cycle
// serial chain latency. Rows/wave: 18 = 4 quads + 1 tail pair.
__global__ __launch_bounds__(1024, 4)
void em_routing_kernel(const float* __restrict__ x,
                       const unsigned short* __restrict__ v,   // [n][i][cq] bf16
                       const float* __restrict__ beta_u,
                       const float* __restrict__ beta_a,
                       float* __restrict__ out)
{
    __shared__ float fct_s[288];            // a/(a+eps)
    __shared__ float red_s[16 * 64 * 17];   // [wave][lane][s0|s1[8]|s2[8]]
    __shared__ float mu_s[32 * 17];
    __shared__ float i2ss_s[32 * 17];
    __shared__ float aout_s[32];
    __shared__ float kc_s[32];

    const int n   = blockIdx.x;
    const int tid = threadIdx.x;
    const int bi = n >> 6, oi = (n >> 3) & 7, oj = n & 7;

    if (tid < 288) {
        int k2 = tid >> 5;
        int c2 = 512 + (tid & 31);
        int f  = k2 * 544 + c2;
        int ci = f / 9;
        int kk = f - ci * 9;
        int row = 2 * oi + kk / 3 - 1;
        int col = 2 * oj + (kk - (kk / 3) * 3) - 1;
        float a = 0.f;
        if ((unsigned)row < 16u && (unsigned)col < 16u)
            a = x[((bi * 16 + row) * 16 + col) * 544 + ci];
        fct_s[tid] = a / (a + EPSV);   // sum_c r*a == a -> rr = softmax * fct
    }
    __syncthreads();

    const unsigned short* vb = v + (size_t)n * 288 * 512;
    const int wv   = tid >> 6;      // wave 0..15
    const int lane = tid & 63;
    const int c    = lane & 31;
    const int qh   = lane >> 5;     // q-half 0/1
    const int qb   = qh * 8;
    const unsigned short* base = vb + c * 16 + qb;

    for (int t = 0; t < 3; ++t) {
        float mu8[8], is8[8], kcv = 0.f;
        if (t > 0) {
            #pragma unroll
            for (int j = 0; j < 8; ++j) {
                mu8[j] = mu_s[c * 17 + qb + j];
                is8[j] = i2ss_s[c * 17 + qb + j];
            }
            kcv = kc_s[c];
        }

        float s0 = 0.f, s1[8], s2[8];
        #pragma unroll
        for (int j = 0; j < 8; ++j) { s1[j] = 0.f; s2[j] = 0.f; }

        // prefetch quad 0 (rows k=0..3; row index = k*16+wv)
        uint4 u0 = *(const uint4*)(base + (size_t)(0 * 16 + wv) * 512);
        uint4 u1 = *(const uint4*)(base + (size_t)(1 * 16 + wv) * 512);
        uint4 u2 = *(const uint4*)(base + (size_t)(2 * 16 + wv) * 512);
        uint4 u3 = *(const uint4*)(base + (size_t)(3 * 16 + wv) * 512);

        #pragma unroll
        for (int g = 0; g < 4; ++g) {
            const int k0 = 4 * g;
            uint4 n0, n1, n2, n3;
            if (g < 3) {   // issue next quad before the compute chains
                n0 = *(const uint4*)(base + (size_t)((k0 + 4) * 16 + wv) * 512);
                n1 = *(const uint4*)(base + (size_t)((k0 + 5) * 16 + wv) * 512);
                n2 = *(const uint4*)(base + (size_t)((k0 + 6) * 16 + wv) * 512);
                n3 = *(const uint4*)(base + (size_t)((k0 + 7) * 16 + wv) * 512);
            } else {       // tail pair rows k=16,17
                n0 = *(const uint4*)(base + (size_t)(16 * 16 + wv) * 512);
                n1 = *(const uint4*)(base + (size_t)(17 * 16 + wv) * 512);
                n2 = n0; n3 = n1;
            }
            const int ia0 = (k0 + 0) * 16 + wv;
            const int ia1 = (k0 + 1) * 16 + wv;
            const int ia2 = (k0 + 2) * 16 + wv;
            const int ia3 = (k0 + 3) * 16 + wv;

            float va0[8], va1[8], va2[8], va3[8];
            expand8(u0, va0); expand8(u1, va1);
            expand8(u2, va2); expand8(u3, va3);

            float rr0, rr1, rr2, rr3;
            if (t == 0) {
                rr0 = fct_s[ia0] * 0.03125f;
                rr1 = fct_s[ia1] * 0.03125f;
                rr2 = fct_s[ia2] * 0.03125f;
                rr3 = fct_s[ia3] * 0.03125f;
            } else {
                float p0 = 0.f, p1 = 0.f, p2 = 0.f, p3 = 0.f;
                #pragma unroll
                for (int j = 0; j < 8; ++j) {
                    float d0 = va0[j] - mu8[j];
                    float d1 = va1[j] - mu8[j];
                    float d2 = va2[j] - mu8[j];
                    float d3 = va3[j] - mu8[j];
                    p0 += d0 * d0 * is8[j];
                    p1 += d1 * d1 * is8[j];
                    p2 += d2 * d2 * is8[j];
                    p3 += d3 * d3 * is8[j];
                }
                p0 = xhalf_sum(p0); p1 = xhalf_sum(p1);
                p2 = xhalf_sum(p2); p3 = xhalf_sum(p3);
                float a0 = kcv - p0, a1 = kcv - p1, a2 = kcv - p2, a3 = kcv - p3;
                float m0 = red_max32(a0), m1 = red_max32(a1);
                float m2 = red_max32(a2), m3 = red_max32(a3);
                float e0 = __expf(a0 - m0), e1 = __expf(a1 - m1);
                float e2 = __expf(a2 - m2), e3 = __expf(a3 - m3);
                float q0 = red_sum32(e0), q1 = red_sum32(e1);
                float q2 = red_sum32(e2), q3 = red_sum32(e3);
                rr0 = (e0 / q0) * fct_s[ia0];
                rr1 = (e1 / q1) * fct_s[ia1];
                rr2 = (e2 / q2) * fct_s[ia2];
                rr3 = (e3 / q3) * fct_s[ia3];
            }

            s0 += (rr0 + rr1) + (rr2 + rr3);
            #pragma unroll
            for (int j = 0; j < 8; ++j) {
                s1[j] += rr0 * va0[j] + rr1 * va1[j] + rr2 * va2[j] + rr3 * va3[j];
                s2[j] += rr0 * va0[j] * va0[j] + rr1 * va1[j] * va1[j]
                       + rr2 * va2[j] * va2[j] + rr3 * va3[j] * va3[j];
            }
            u0 = n0; u1 = n1; u2 = n2; u3 = n3;
        }

        // tail pair: rows k=16 (u0), k=17 (u1)
        {
            const int ia0 = 16 * 16 + wv;
            const int ia1 = 17 * 16 + wv;
            float va0[8], va1[8];
            expand8(u0, va0); expand8(u1, va1);
            float rr0, rr1;
            if (t == 0) {
                rr0 = fct_s[ia0] * 0.03125f;
                rr1 = fct_s[ia1] * 0.03125f;
            } else {
                float p0 = 0.f, p1 = 0.f;
                #pragma unroll
                for (int j = 0; j < 8; ++j) {
                    float d0 = va0[j] - mu8[j];
                    float d1 = va1[j] - mu8[j];
                    p0 += d0 * d0 * is8[j];
                    p1 += d1 * d1 * is8[j];
                }
                p0 = xhalf_sum(p0); p1 = xhalf_sum(p1);
                float a0 = kcv - p0, a1 = kcv - p1;
                float m0 = red_max32(a0), m1 = red_max32(a1);
                float e0 = __expf(a0 - m0), e1 = __expf(a1 - m1);
                float q0 = red_sum32(e0), q1 = red_sum32(e1);
                rr0 = (e0 / q0) * fct_s[ia0];
                rr1 = (e1 / q1) * fct_s[ia1];
            }
            s0 += rr0 + rr1;
            #pragma unroll
            for (int j = 0; j < 8; ++j) {
                s1[j] += rr0 * va0[j] + rr1 * va1[j];
                s2[j] += rr0 * va0[j] * va0[j] + rr1 * va1[j] * va1[j];
            }
        }

        // per-wave partials -> LDS (stride 17: 2-way bank alias = free)
        {
            float* dst = &red_s[(wv * 64 + lane) * 17];
            dst[0] = s0;
            #pragma unroll
            for (int j = 0; j < 8; ++j) { dst[1 + j] = s1[j]; dst[9 + j] = s2[j]; }
        }
        __syncthreads();

        // final 16-way reduce + mu/sigma + fused a_out (thread = (c2,q2))
        if (tid < 512) {
            const int c2 = tid >> 4, q2 = tid & 15;
            const int qh2 = q2 >> 3, j2 = q2 & 7;
            float S0 = 0.f, S1 = 0.f, S2 = 0.f;
            #pragma unroll
            for (int wvi = 0; wvi < 16; ++wvi) {
                S0 += red_s[(wvi * 64 + c2) * 17];
                const float* sp = &red_s[(wvi * 64 + qh2 * 32 + c2) * 17];
                S1 += sp[1 + j2];
                S2 += sp[9 + j2];
            }
            float invr = 1.0f / (S0 + EPSV);
            float w0  = S0 * invr;
            float m   = S1 * invr;
            float s2p = S2 * invr;
            float sig = s2p - m * m * (2.0f - w0);   // == sum coeff*(v-mu)^2
            sig = fmaxf(sig + EPSV, 1e-4f);
            float hl = 0.5f * logf(sig);
            mu_s[c2 * 17 + q2]   = m;
            i2ss_s[c2 * 17 + q2] = 1.0f / (2.0f * sig);
            // fused old phase-3: 16-lane DPP row (one c2 per row) sums hl
            float shl = red_sum16(hl);
            if (q2 == 0) {
                float bu  = beta_u[c2];
                float cs  = (16.0f * bu + shl) * S0;
                float arg = LAMBDAV * (beta_a[c2] - cs);
                float ao  = 1.0f / (1.0f + expf(-arg));
                ao = fminf(fmaxf(ao, 1e-4f), 1.0f - 1e-4f);
                aout_s[c2] = ao;
                kc_s[c2]   = logf(ao + EPSV) - shl - 8.0f * LN_2PI;
            }
        }
        __syncthreads();
    }

    // epilogue (fp32): p_out [0,65536) | a_out [65536,69632) | out [69632,139264)
    if (tid < 512) {
        int c2 = tid >> 4, q2 = tid & 15;
        float mu = mu_s[c2 * 17 + q2];
        if (isnan(mu)) mu = 0.f;
        mu = fminf(fmaxf(mu, -10000.f), 10000.f);
        out[(size_t)n * 512 + tid] = mu;
        out[69632 + (size_t)n * 544 + tid] = mu;
        if (tid < 32) {
            float ao = aout_s[tid];
            if (isnan(ao)) ao = 0.5f;
            out[65536 + n * 32 + tid] = ao;
            out[69632 + n * 544 + 512 + tid] = ao;
        }
    }
}

extern "C" void kernel_launch(void* const* d_in, const int* in_sizes, int n_in,
                              void* d_out, int out_size, void* d_ws, size_t ws_size,
                              hipStream_t stream) {
    const float* x  = (const float*)d_in[0];
    const float* w  = (const float*)d_in[1];
    const float* bu = (const float*)d_in[2];
    const float* ba = (const float*)d_in[3];
    float* out = (float*)d_out;
    __hip_bfloat16* v = (__hip_bfloat16*)d_ws;  // 128*288*512 bf16 = 37.7 MB

    conv_v_kernel<<<dim3(576), dim3(256), 0, stream>>>(x, w, v);
    em_routing_kernel<<<dim3(128), dim3(1024), 0, stream>>>(
        x, (const unsigned short*)v, bu, ba, out);
}

// Round 6
// 207.181 us; speedup vs baseline: 1.1847x; 1.1847x over previous
//
#include <hip/hip_runtime.h>
#include <hip/hip_bf16.h>
#include <math.h>

#define EPSV 1e-6f
#define LAMBDAV 1e-3f
#define LN_2PI 1.8378770664093453f

__device__ __forceinline__ float bflo(unsigned int u) {
    union { unsigned int i; float f; } x; x.i = u << 16; return x.f;
}
__device__ __forceinline__ float bfhi(unsigned int u) {
    union { unsigned int i; float f; } x; x.i = u & 0xffff0000u; return x.f;
}
__device__ __forceinline__ unsigned short f2bf(float f) {
    __hip_bfloat16 h = __float2bfloat16(f);
    return *(unsigned short*)&h;
}

typedef __attribute__((ext_vector_type(8))) short s8v;
typedef __attribute__((ext_vector_type(4))) float f4v;
typedef __attribute__((ext_vector_type(2))) int i2v;
typedef __attribute__((ext_vector_type(8))) float f8v8;

// DPP lane-permute move (VALU-latency cross-lane, no LDS pipe).
template<int CTRL>
__device__ __forceinline__ float dpp_mv(float x) {
    return __int_as_float(__builtin_amdgcn_update_dpp(
        0, __float_as_int(x), CTRL, 0xF, 0xF, true));
}
__device__ __forceinline__ float x16_sum(float x) {
#if __has_builtin(__builtin_amdgcn_permlane16_swap)
    i2v r = __builtin_amdgcn_permlane16_swap(__float_as_int(x), __float_as_int(x), false, false);
    return __int_as_float(r.x) + __int_as_float(r.y);
#else
    return x + __int_as_float(__builtin_amdgcn_ds_swizzle(__float_as_int(x), 0x401F));
#endif
}
__device__ __forceinline__ float x16_max(float x) {
#if __has_builtin(__builtin_amdgcn_permlane16_swap)
    i2v r = __builtin_amdgcn_permlane16_swap(__float_as_int(x), __float_as_int(x), false, false);
    return fmaxf(__int_as_float(r.x), __int_as_float(r.y));
#else
    return fmaxf(x, __int_as_float(__builtin_amdgcn_ds_swizzle(__float_as_int(x), 0x401F)));
#endif
}
__device__ __forceinline__ float xhalf_sum(float x) {
#if __has_builtin(__builtin_amdgcn_permlane32_swap)
    i2v r = __builtin_amdgcn_permlane32_swap(__float_as_int(x), __float_as_int(x), false, false);
    return __int_as_float(r.x) + __int_as_float(r.y);
#else
    return x + __shfl_xor(x, 32, 64);
#endif
}
__device__ __forceinline__ float red_max32(float x) {
    x = fmaxf(x, dpp_mv<0xB1>(x));    // quad_perm [1,0,3,2]  (xor 1)
    x = fmaxf(x, dpp_mv<0x4E>(x));    // quad_perm [2,3,0,1]  (xor 2)
    x = fmaxf(x, dpp_mv<0x124>(x));   // row_ror:4
    x = fmaxf(x, dpp_mv<0x128>(x));   // row_ror:8
    return x16_max(x);
}
__device__ __forceinline__ float red_sum32(float x) {
    x += dpp_mv<0xB1>(x);
    x += dpp_mv<0x4E>(x);
    x += dpp_mv<0x124>(x);
    x += dpp_mv<0x128>(x);
    return x16_sum(x);
}
__device__ __forceinline__ float red_sum16(float x) {
    x += dpp_mv<0xB1>(x);
    x += dpp_mv<0x4E>(x);
    x += dpp_mv<0x124>(x);
    x += dpp_mv<0x128>(x);
    return x;
}
// By-value ext_vector expansion: guaranteed register-resident (no pointer
// param -> no SROA failure -> no scratch; the R5 lesson).
__device__ __forceinline__ f8v8 expand8v(uint4 u) {
    f8v8 r;
    r[0] = bflo(u.x); r[1] = bfhi(u.x);
    r[2] = bflo(u.y); r[3] = bfhi(u.y);
    r[4] = bflo(u.z); r[5] = bfhi(u.z);
    r[6] = bflo(u.w); r[7] = bfhi(u.w);
    return r;
}

// Kernel 1: MFMA conv, M-split: 576 blocks = (i2, cq-half). 30KB LDS/block ->
// ~5 blocks/CU capacity, removes the 288=256+32 two-round quantization.
__global__ __launch_bounds__(256)
void conv_v_kernel(const float* __restrict__ x, const float* __restrict__ w,
                   __hip_bfloat16* __restrict__ vout)
{
    __shared__ unsigned short wb[256 * 40];  // [cq_local][p pad40]
    __shared__ unsigned short pb[128 * 40];  // [n][p pad40]

    const int bid = blockIdx.x;
    const int i2  = bid >> 1;
    const int mh  = bid & 1;                 // cq half: [mh*256, mh*256+256)
    const int tid = threadIdx.x;

    // zero k=16..31 padding (mfma reads k<32)
    for (int u = tid; u < 256 * 8; u += 256) {
        int r = u >> 3, j = u & 7;
        *(unsigned int*)&wb[r * 40 + 16 + j * 2] = 0;
    }
    for (int u = tid; u < 128 * 8; u += 256) {
        int r = u >> 3, j = u & 7;
        *(unsigned int*)&pb[r * 40 + 16 + j * 2] = 0;
    }
    // stage w[i2][c][p][q] fp32 -> wb[(c_local*16+q)][p] bf16 for c_local 0..15
    #pragma unroll 4
    for (int u = 0; u < 16; ++u) {
        int idx = u * 256 + tid;               // cl*256 + p*16 + q
        int cl = idx >> 8, p = (idx >> 4) & 15, q = idx & 15;
        wb[(cl * 16 + q) * 40 + p] = f2bf(w[(size_t)i2 * 8192 + mh * 4096 + idx]);
    }
    // fused gather: pb[nn][p] from x via reference reshape scramble
    #pragma unroll
    for (int u = 0; u < 8; ++u) {
        int idx = u * 256 + tid;               // nn*16 + p
        int nn = idx >> 4, p = idx & 15;
        int e  = i2 * 16 + p;
        int k2 = e >> 9, c2 = e & 511;
        int f  = k2 * 544 + c2;
        int ci = f / 9, kk = f - ci * 9;
        int bi = nn >> 6, oi = (nn >> 3) & 7, oj = nn & 7;
        int row = 2 * oi + kk / 3 - 1;
        int col = 2 * oj + (kk - (kk / 3) * 3) - 1;
        float val = 0.f;
        if ((unsigned)row < 16u && (unsigned)col < 16u)
            val = x[((bi * 16 + row) * 16 + col) * 544 + ci];
        pb[nn * 40 + p] = f2bf(val);
    }
    __syncthreads();

    const int lane = tid & 63;
    const int wv   = tid >> 6;
    const int l16  = lane & 15;
    const int quad = lane >> 4;
    const int cq0l = wv * 64;                  // local cq base of this wave

    s8v afrag[4], bfrag[8];
    #pragma unroll
    for (int mt = 0; mt < 4; ++mt)
        afrag[mt] = *(const s8v*)&wb[(cq0l + mt * 16 + l16) * 40 + quad * 8];
    #pragma unroll
    for (int nt = 0; nt < 8; ++nt)
        bfrag[nt] = *(const s8v*)&pb[(nt * 16 + l16) * 40 + quad * 8];

    #pragma unroll
    for (int nt = 0; nt < 8; ++nt) {
        const int nl = nt * 16 + l16;
        #pragma unroll
        for (int mt = 0; mt < 4; ++mt) {
            f4v acc = {0.f, 0.f, 0.f, 0.f};
            acc = __builtin_amdgcn_mfma_f32_16x16x32_bf16(afrag[mt], bfrag[nt], acc, 0, 0, 0);
            int cq = mh * 256 + cq0l + mt * 16 + quad * 4;
            unsigned int lo = f2bf(acc[0]) | ((unsigned int)f2bf(acc[1]) << 16);
            unsigned int hi = f2bf(acc[2]) | ((unsigned int)f2bf(acc[3]) << 16);
            uint2 pk; pk.x = lo; pk.y = hi;
            *(uint2*)((unsigned short*)vout + ((size_t)nl * 288 + i2) * 512 + cq) = pk;
        }
    }
}

// Kernel 2: EM routing. R4 structure (one block per n, 16 waves, lane =
// (qh,c), VALU-pipe cross-lane) + 4-row ILP with register-proof by-value
// ext_vector expansion (R5's pointer-param arrays went to scratch).
// Rows/wave: 18 = 4 quads + 1 tail pair.
__global__ __launch_bounds__(1024, 4)
void em_routing_kernel(const float* __restrict__ x,
                       const unsigned short* __restrict__ v,   // [n][i][cq] bf16
                       const float* __restrict__ beta_u,
                       const float* __restrict__ beta_a,
                       float* __restrict__ out)
{
    __shared__ float fct_s[288];            // a/(a+eps)
    __shared__ float red_s[16 * 64 * 17];   // [wave][lane][s0|s1[8]|s2[8]]
    __shared__ float mu_s[32 * 17];
    __shared__ float i2ss_s[32 * 17];
    __shared__ float aout_s[32];
    __shared__ float kc_s[32];

    const int n   = blockIdx.x;
    const int tid = threadIdx.x;
    const int bi = n >> 6, oi = (n >> 3) & 7, oj = n & 7;

    if (tid < 288) {
        int k2 = tid >> 5;
        int c2 = 512 + (tid & 31);
        int f  = k2 * 544 + c2;
        int ci = f / 9;
        int kk = f - ci * 9;
        int row = 2 * oi + kk / 3 - 1;
        int col = 2 * oj + (kk - (kk / 3) * 3) - 1;
        float a = 0.f;
        if ((unsigned)row < 16u && (unsigned)col < 16u)
            a = x[((bi * 16 + row) * 16 + col) * 544 + ci];
        fct_s[tid] = a / (a + EPSV);   // sum_c r*a == a -> rr = softmax * fct
    }
    __syncthreads();

    const unsigned short* vb = v + (size_t)n * 288 * 512;
    const int wv   = tid >> 6;      // wave 0..15
    const int lane = tid & 63;
    const int c    = lane & 31;
    const int qh   = lane >> 5;     // q-half 0/1
    const int qb   = qh * 8;
    const unsigned short* base = vb + c * 16 + qb;

    for (int t = 0; t < 3; ++t) {
        float mu8[8], is8[8], kcv = 0.f;
        if (t > 0) {
            #pragma unroll
            for (int j = 0; j < 8; ++j) {
                mu8[j] = mu_s[c * 17 + qb + j];
                is8[j] = i2ss_s[c * 17 + qb + j];
            }
            kcv = kc_s[c];
        }

        float s0 = 0.f, s1[8], s2[8];
        #pragma unroll
        for (int j = 0; j < 8; ++j) { s1[j] = 0.f; s2[j] = 0.f; }

        // prefetch quad 0 (rows k=0..3; row index = k*16+wv)
        uint4 u0 = *(const uint4*)(base + (size_t)(0 * 16 + wv) * 512);
        uint4 u1 = *(const uint4*)(base + (size_t)(1 * 16 + wv) * 512);
        uint4 u2 = *(const uint4*)(base + (size_t)(2 * 16 + wv) * 512);
        uint4 u3 = *(const uint4*)(base + (size_t)(3 * 16 + wv) * 512);

        #pragma unroll
        for (int g = 0; g < 4; ++g) {
            const int k0 = 4 * g;
            uint4 n0, n1, n2, n3;
            if (g < 3) {   // issue next quad before the compute chains
                n0 = *(const uint4*)(base + (size_t)((k0 + 4) * 16 + wv) * 512);
                n1 = *(const uint4*)(base + (size_t)((k0 + 5) * 16 + wv) * 512);
                n2 = *(const uint4*)(base + (size_t)((k0 + 6) * 16 + wv) * 512);
                n3 = *(const uint4*)(base + (size_t)((k0 + 7) * 16 + wv) * 512);
            } else {       // tail pair rows k=16,17
                n0 = *(const uint4*)(base + (size_t)(16 * 16 + wv) * 512);
                n1 = *(const uint4*)(base + (size_t)(17 * 16 + wv) * 512);
                n2 = n0; n3 = n1;
            }
            const int ia0 = (k0 + 0) * 16 + wv;
            const int ia1 = (k0 + 1) * 16 + wv;
            const int ia2 = (k0 + 2) * 16 + wv;
            const int ia3 = (k0 + 3) * 16 + wv;

            f8v8 va0 = expand8v(u0), va1 = expand8v(u1);
            f8v8 va2 = expand8v(u2), va3 = expand8v(u3);

            float rr0, rr1, rr2, rr3;
            if (t == 0) {
                rr0 = fct_s[ia0] * 0.03125f;
                rr1 = fct_s[ia1] * 0.03125f;
                rr2 = fct_s[ia2] * 0.03125f;
                rr3 = fct_s[ia3] * 0.03125f;
            } else {
                float p0 = 0.f, p1 = 0.f, p2 = 0.f, p3 = 0.f;
                #pragma unroll
                for (int j = 0; j < 8; ++j) {
                    float d0 = va0[j] - mu8[j];
                    float d1 = va1[j] - mu8[j];
                    float d2 = va2[j] - mu8[j];
                    float d3 = va3[j] - mu8[j];
                    p0 += d0 * d0 * is8[j];
                    p1 += d1 * d1 * is8[j];
                    p2 += d2 * d2 * is8[j];
                    p3 += d3 * d3 * is8[j];
                }
                p0 = xhalf_sum(p0); p1 = xhalf_sum(p1);
                p2 = xhalf_sum(p2); p3 = xhalf_sum(p3);
                float a0 = kcv - p0, a1 = kcv - p1, a2 = kcv - p2, a3 = kcv - p3;
                float m0 = red_max32(a0), m1 = red_max32(a1);
                float m2 = red_max32(a2), m3 = red_max32(a3);
                float e0 = __expf(a0 - m0), e1 = __expf(a1 - m1);
                float e2 = __expf(a2 - m2), e3 = __expf(a3 - m3);
                float q0 = red_sum32(e0), q1 = red_sum32(e1);
                float q2 = red_sum32(e2), q3 = red_sum32(e3);
                rr0 = (e0 / q0) * fct_s[ia0];
                rr1 = (e1 / q1) * fct_s[ia1];
                rr2 = (e2 / q2) * fct_s[ia2];
                rr3 = (e3 / q3) * fct_s[ia3];
            }

            s0 += (rr0 + rr1) + (rr2 + rr3);
            #pragma unroll
            for (int j = 0; j < 8; ++j) {
                s1[j] += rr0 * va0[j] + rr1 * va1[j] + rr2 * va2[j] + rr3 * va3[j];
                s2[j] += rr0 * va0[j] * va0[j] + rr1 * va1[j] * va1[j]
                       + rr2 * va2[j] * va2[j] + rr3 * va3[j] * va3[j];
            }
            u0 = n0; u1 = n1; u2 = n2; u3 = n3;
        }

        // tail pair: rows k=16 (u0), k=17 (u1)
        {
            const int ia0 = 16 * 16 + wv;
            const int ia1 = 17 * 16 + wv;
            f8v8 va0 = expand8v(u0), va1 = expand8v(u1);
            float rr0, rr1;
            if (t == 0) {
                rr0 = fct_s[ia0] * 0.03125f;
                rr1 = fct_s[ia1] * 0.03125f;
            } else {
                float p0 = 0.f, p1 = 0.f;
                #pragma unroll
                for (int j = 0; j < 8; ++j) {
                    float d0 = va0[j] - mu8[j];
                    float d1 = va1[j] - mu8[j];
                    p0 += d0 * d0 * is8[j];
                    p1 += d1 * d1 * is8[j];
                }
                p0 = xhalf_sum(p0); p1 = xhalf_sum(p1);
                float a0 = kcv - p0, a1 = kcv - p1;
                float m0 = red_max32(a0), m1 = red_max32(a1);
                float e0 = __expf(a0 - m0), e1 = __expf(a1 - m1);
                float q0 = red_sum32(e0), q1 = red_sum32(e1);
                rr0 = (e0 / q0) * fct_s[ia0];
                rr1 = (e1 / q1) * fct_s[ia1];
            }
            s0 += rr0 + rr1;
            #pragma unroll
            for (int j = 0; j < 8; ++j) {
                s1[j] += rr0 * va0[j] + rr1 * va1[j];
                s2[j] += rr0 * va0[j] * va0[j] + rr1 * va1[j] * va1[j];
            }
        }

        // per-wave partials -> LDS (stride 17: 2-way bank alias = free)
        {
            float* dst = &red_s[(wv * 64 + lane) * 17];
            dst[0] = s0;
            #pragma unroll
            for (int j = 0; j < 8; ++j) { dst[1 + j] = s1[j]; dst[9 + j] = s2[j]; }
        }
        __syncthreads();

        // final 16-way reduce + mu/sigma + fused a_out (thread = (c2,q2))
        if (tid < 512) {
            const int c2 = tid >> 4, q2 = tid & 15;
            const int qh2 = q2 >> 3, j2 = q2 & 7;
            float S0 = 0.f, S1 = 0.f, S2 = 0.f;
            #pragma unroll
            for (int wvi = 0; wvi < 16; ++wvi) {
                S0 += red_s[(wvi * 64 + c2) * 17];
                const float* sp = &red_s[(wvi * 64 + qh2 * 32 + c2) * 17];
                S1 += sp[1 + j2];
                S2 += sp[9 + j2];
            }
            float invr = 1.0f / (S0 + EPSV);
            float w0  = S0 * invr;
            float m   = S1 * invr;
            float s2p = S2 * invr;
            float sig = s2p - m * m * (2.0f - w0);   // == sum coeff*(v-mu)^2
            sig = fmaxf(sig + EPSV, 1e-4f);
            float hl = 0.5f * logf(sig);
            mu_s[c2 * 17 + q2]   = m;
            i2ss_s[c2 * 17 + q2] = 1.0f / (2.0f * sig);
            // fused old phase-3: 16-lane DPP row (one c2 per row) sums hl
            float shl = red_sum16(hl);
            if (q2 == 0) {
                float bu  = beta_u[c2];
                float cs  = (16.0f * bu + shl) * S0;
                float arg = LAMBDAV * (beta_a[c2] - cs);
                float ao  = 1.0f / (1.0f + expf(-arg));
                ao = fminf(fmaxf(ao, 1e-4f), 1.0f - 1e-4f);
                aout_s[c2] = ao;
                kc_s[c2]   = logf(ao + EPSV) - shl - 8.0f * LN_2PI;
            }
        }
        __syncthreads();
    }

    // epilogue (fp32): p_out [0,65536) | a_out [65536,69632) | out [69632,139264)
    if (tid < 512) {
        int c2 = tid >> 4, q2 = tid & 15;
        float mu = mu_s[c2 * 17 + q2];
        if (isnan(mu)) mu = 0.f;
        mu = fminf(fmaxf(mu, -10000.f), 10000.f);
        out[(size_t)n * 512 + tid] = mu;
        out[69632 + (size_t)n * 544 + tid] = mu;
        if (tid < 32) {
            float ao = aout_s[tid];
            if (isnan(ao)) ao = 0.5f;
            out[65536 + n * 32 + tid] = ao;
            out[69632 + n * 544 + 512 + tid] = ao;
        }
    }
}

extern "C" void kernel_launch(void* const* d_in, const int* in_sizes, int n_in,
                              void* d_out, int out_size, void* d_ws, size_t ws_size,
                              hipStream_t stream) {
    const float* x  = (const float*)d_in[0];
    const float* w  = (const float*)d_in[1];
    const float* bu = (const float*)d_in[2];
    const float* ba = (const float*)d_in[3];
    float* out = (float*)d_out;
    __hip_bfloat16* v = (__hip_bfloat16*)d_ws;  // 128*288*512 bf16 = 37.7 MB

    conv_v_kernel<<<dim3(576), dim3(256), 0, stream>>>(x, w, v);
    em_routing_kernel<<<dim3(128), dim3(1024), 0, stream>>>(
        x, (const unsigned short*)v, bu, ba, out);
}

// Round 7
// 206.588 us; speedup vs baseline: 1.1881x; 1.0029x over previous
//
#include <hip/hip_runtime.h>
#include <hip/hip_bf16.h>
#include <math.h>

#define EPSV 1e-6f
#define LAMBDAV 1e-3f
#define LN_2PI 1.8378770664093453f

__device__ __forceinline__ float bflo(unsigned int u) {
    union { unsigned int i; float f; } x; x.i = u << 16; return x.f;
}
__device__ __forceinline__ float bfhi(unsigned int u) {
    union { unsigned int i; float f; } x; x.i = u & 0xffff0000u; return x.f;
}
__device__ __forceinline__ unsigned short f2bf(float f) {
    __hip_bfloat16 h = __float2bfloat16(f);
    return *(unsigned short*)&h;
}

typedef __attribute__((ext_vector_type(8))) short s8v;
typedef __attribute__((ext_vector_type(4))) float f4v;
typedef __attribute__((ext_vector_type(2))) int i2v;
typedef __attribute__((ext_vector_type(8))) float f8v8;

// DPP lane-permute move (VALU-latency cross-lane, no LDS pipe).
template<int CTRL>
__device__ __forceinline__ float dpp_mv(float x) {
    return __int_as_float(__builtin_amdgcn_update_dpp(
        0, __float_as_int(x), CTRL, 0xF, 0xF, true));
}
__device__ __forceinline__ float x16_sum(float x) {
#if __has_builtin(__builtin_amdgcn_permlane16_swap)
    i2v r = __builtin_amdgcn_permlane16_swap(__float_as_int(x), __float_as_int(x), false, false);
    return __int_as_float(r.x) + __int_as_float(r.y);
#else
    return x + __int_as_float(__builtin_amdgcn_ds_swizzle(__float_as_int(x), 0x401F));
#endif
}
__device__ __forceinline__ float x16_max(float x) {
#if __has_builtin(__builtin_amdgcn_permlane16_swap)
    i2v r = __builtin_amdgcn_permlane16_swap(__float_as_int(x), __float_as_int(x), false, false);
    return fmaxf(__int_as_float(r.x), __int_as_float(r.y));
#else
    return fmaxf(x, __int_as_float(__builtin_amdgcn_ds_swizzle(__float_as_int(x), 0x401F)));
#endif
}
__device__ __forceinline__ float xhalf_sum(float x) {
#if __has_builtin(__builtin_amdgcn_permlane32_swap)
    i2v r = __builtin_amdgcn_permlane32_swap(__float_as_int(x), __float_as_int(x), false, false);
    return __int_as_float(r.x) + __int_as_float(r.y);
#else
    return x + __shfl_xor(x, 32, 64);
#endif
}
__device__ __forceinline__ float red_max32(float x) {
    x = fmaxf(x, dpp_mv<0xB1>(x));    // quad_perm [1,0,3,2]  (xor 1)
    x = fmaxf(x, dpp_mv<0x4E>(x));    // quad_perm [2,3,0,1]  (xor 2)
    x = fmaxf(x, dpp_mv<0x124>(x));   // row_ror:4
    x = fmaxf(x, dpp_mv<0x128>(x));   // row_ror:8
    return x16_max(x);
}
__device__ __forceinline__ float red_sum32(float x) {
    x += dpp_mv<0xB1>(x);
    x += dpp_mv<0x4E>(x);
    x += dpp_mv<0x124>(x);
    x += dpp_mv<0x128>(x);
    return x16_sum(x);
}
__device__ __forceinline__ float red_sum16(float x) {
    x += dpp_mv<0xB1>(x);
    x += dpp_mv<0x4E>(x);
    x += dpp_mv<0x124>(x);
    x += dpp_mv<0x128>(x);
    return x;
}
// By-value ext_vector expansion: register-resident (no pointer param).
__device__ __forceinline__ f8v8 expand8v(uint4 u) {
    f8v8 r;
    r[0] = bflo(u.x); r[1] = bfhi(u.x);
    r[2] = bflo(u.y); r[3] = bfhi(u.y);
    r[4] = bflo(u.z); r[5] = bfhi(u.z);
    r[6] = bflo(u.w); r[7] = bfhi(u.w);
    return r;
}

// Kernel 1: MFMA conv, M-split: 576 blocks = (i2, cq-half). 30KB LDS/block ->
// ~5 blocks/CU capacity, removes the 288=256+32 two-round quantization.
__global__ __launch_bounds__(256)
void conv_v_kernel(const float* __restrict__ x, const float* __restrict__ w,
                   __hip_bfloat16* __restrict__ vout)
{
    __shared__ unsigned short wb[256 * 40];  // [cq_local][p pad40]
    __shared__ unsigned short pb[128 * 40];  // [n][p pad40]

    const int bid = blockIdx.x;
    const int i2  = bid >> 1;
    const int mh  = bid & 1;                 // cq half: [mh*256, mh*256+256)
    const int tid = threadIdx.x;

    // zero k=16..31 padding (mfma reads k<32)
    for (int u = tid; u < 256 * 8; u += 256) {
        int r = u >> 3, j = u & 7;
        *(unsigned int*)&wb[r * 40 + 16 + j * 2] = 0;
    }
    for (int u = tid; u < 128 * 8; u += 256) {
        int r = u >> 3, j = u & 7;
        *(unsigned int*)&pb[r * 40 + 16 + j * 2] = 0;
    }
    // stage w[i2][c][p][q] fp32 -> wb[(c_local*16+q)][p] bf16 for c_local 0..15
    #pragma unroll 4
    for (int u = 0; u < 16; ++u) {
        int idx = u * 256 + tid;               // cl*256 + p*16 + q
        int cl = idx >> 8, p = (idx >> 4) & 15, q = idx & 15;
        wb[(cl * 16 + q) * 40 + p] = f2bf(w[(size_t)i2 * 8192 + mh * 4096 + idx]);
    }
    // fused gather: pb[nn][p] from x via reference reshape scramble
    #pragma unroll
    for (int u = 0; u < 8; ++u) {
        int idx = u * 256 + tid;               // nn*16 + p
        int nn = idx >> 4, p = idx & 15;
        int e  = i2 * 16 + p;
        int k2 = e >> 9, c2 = e & 511;
        int f  = k2 * 544 + c2;
        int ci = f / 9, kk = f - ci * 9;
        int bi = nn >> 6, oi = (nn >> 3) & 7, oj = nn & 7;
        int row = 2 * oi + kk / 3 - 1;
        int col = 2 * oj + (kk - (kk / 3) * 3) - 1;
        float val = 0.f;
        if ((unsigned)row < 16u && (unsigned)col < 16u)
            val = x[((bi * 16 + row) * 16 + col) * 544 + ci];
        pb[nn * 40 + p] = f2bf(val);
    }
    __syncthreads();

    const int lane = tid & 63;
    const int wv   = tid >> 6;
    const int l16  = lane & 15;
    const int quad = lane >> 4;
    const int cq0l = wv * 64;                  // local cq base of this wave

    s8v afrag[4], bfrag[8];
    #pragma unroll
    for (int mt = 0; mt < 4; ++mt)
        afrag[mt] = *(const s8v*)&wb[(cq0l + mt * 16 + l16) * 40 + quad * 8];
    #pragma unroll
    for (int nt = 0; nt < 8; ++nt)
        bfrag[nt] = *(const s8v*)&pb[(nt * 16 + l16) * 40 + quad * 8];

    #pragma unroll
    for (int nt = 0; nt < 8; ++nt) {
        const int nl = nt * 16 + l16;
        #pragma unroll
        for (int mt = 0; mt < 4; ++mt) {
            f4v acc = {0.f, 0.f, 0.f, 0.f};
            acc = __builtin_amdgcn_mfma_f32_16x16x32_bf16(afrag[mt], bfrag[nt], acc, 0, 0, 0);
            int cq = mh * 256 + cq0l + mt * 16 + quad * 4;
            unsigned int lo = f2bf(acc[0]) | ((unsigned int)f2bf(acc[1]) << 16);
            unsigned int hi = f2bf(acc[2]) | ((unsigned int)f2bf(acc[3]) << 16);
            uint2 pk; pk.x = lo; pk.y = hi;
            *(uint2*)((unsigned short*)vout + ((size_t)nl * 288 + i2) * 512 + cq) = pk;
        }
    }
}

// Kernel 2: EM routing. R6 body (4-row ILP) + allocator fix: LDS padded past
// 80KiB so only 1 block/CU fits -> backend occupancy target drops from
// 8 waves/SIMD (VGPR cap 64, the R5/R6 spill source) to 4 waves/SIMD
// (cap 128); amdgpu_waves_per_eu(4,4) pins it. Grid=128 on 256 CUs means
// 2-block packing never happened at runtime anyway.
__global__ __launch_bounds__(1024)
__attribute__((amdgpu_waves_per_eu(4, 4)))
void em_routing_kernel(const float* __restrict__ x,
                       const unsigned short* __restrict__ v,   // [n][i][cq] bf16
                       const float* __restrict__ beta_u,
                       const float* __restrict__ beta_a,
                       float* __restrict__ out)
{
    __shared__ float fct_s[288];            // a/(a+eps)
    __shared__ float red_s[16 * 64 * 17];   // [wave][lane][s0|s1[8]|s2[8]]
    __shared__ float mu_s[32 * 17];
    __shared__ float i2ss_s[32 * 17];
    __shared__ float aout_s[32];
    __shared__ float kc_s[32];
    __shared__ float pad_s[2176];           // occupancy limiter: LDS > 80KiB

    const int n   = blockIdx.x;
    const int tid = threadIdx.x;
    const int bi = n >> 6, oi = (n >> 3) & 7, oj = n & 7;

    // volatile store: cannot be DCE'd, so pad_s stays allocated (R3's plain
    // guarded store was eliminated - LDS_Block_Size proved it).
    ((volatile float*)pad_s)[tid & 1023] = 0.f;

    if (tid < 288) {
        int k2 = tid >> 5;
        int c2 = 512 + (tid & 31);
        int f  = k2 * 544 + c2;
        int ci = f / 9;
        int kk = f - ci * 9;
        int row = 2 * oi + kk / 3 - 1;
        int col = 2 * oj + (kk - (kk / 3) * 3) - 1;
        float a = 0.f;
        if ((unsigned)row < 16u && (unsigned)col < 16u)
            a = x[((bi * 16 + row) * 16 + col) * 544 + ci];
        fct_s[tid] = a / (a + EPSV);   // sum_c r*a == a -> rr = softmax * fct
    }
    __syncthreads();

    const unsigned short* vb = v + (size_t)n * 288 * 512;
    const int wv   = tid >> 6;      // wave 0..15
    const int lane = tid & 63;
    const int c    = lane & 31;
    const int qh   = lane >> 5;     // q-half 0/1
    const int qb   = qh * 8;
    const unsigned short* base = vb + c * 16 + qb;

    for (int t = 0; t < 3; ++t) {
        float mu8[8], is8[8], kcv = 0.f;
        if (t > 0) {
            #pragma unroll
            for (int j = 0; j < 8; ++j) {
                mu8[j] = mu_s[c * 17 + qb + j];
                is8[j] = i2ss_s[c * 17 + qb + j];
            }
            kcv = kc_s[c];
        }

        float s0 = 0.f, s1[8], s2[8];
        #pragma unroll
        for (int j = 0; j < 8; ++j) { s1[j] = 0.f; s2[j] = 0.f; }

        // prefetch quad 0 (rows k=0..3; row index = k*16+wv)
        uint4 u0 = *(const uint4*)(base + (size_t)(0 * 16 + wv) * 512);
        uint4 u1 = *(const uint4*)(base + (size_t)(1 * 16 + wv) * 512);
        uint4 u2 = *(const uint4*)(base + (size_t)(2 * 16 + wv) * 512);
        uint4 u3 = *(const uint4*)(base + (size_t)(3 * 16 + wv) * 512);

        #pragma unroll
        for (int g = 0; g < 4; ++g) {
            const int k0 = 4 * g;
            uint4 n0, n1, n2, n3;
            if (g < 3) {   // issue next quad before the compute chains
                n0 = *(const uint4*)(base + (size_t)((k0 + 4) * 16 + wv) * 512);
                n1 = *(const uint4*)(base + (size_t)((k0 + 5) * 16 + wv) * 512);
                n2 = *(const uint4*)(base + (size_t)((k0 + 6) * 16 + wv) * 512);
                n3 = *(const uint4*)(base + (size_t)((k0 + 7) * 16 + wv) * 512);
            } else {       // tail pair rows k=16,17
                n0 = *(const uint4*)(base + (size_t)(16 * 16 + wv) * 512);
                n1 = *(const uint4*)(base + (size_t)(17 * 16 + wv) * 512);
                n2 = n0; n3 = n1;
            }
            const int ia0 = (k0 + 0) * 16 + wv;
            const int ia1 = (k0 + 1) * 16 + wv;
            const int ia2 = (k0 + 2) * 16 + wv;
            const int ia3 = (k0 + 3) * 16 + wv;

            f8v8 va0 = expand8v(u0), va1 = expand8v(u1);
            f8v8 va2 = expand8v(u2), va3 = expand8v(u3);

            float rr0, rr1, rr2, rr3;
            if (t == 0) {
                rr0 = fct_s[ia0] * 0.03125f;
                rr1 = fct_s[ia1] * 0.03125f;
                rr2 = fct_s[ia2] * 0.03125f;
                rr3 = fct_s[ia3] * 0.03125f;
            } else {
                float p0 = 0.f, p1 = 0.f, p2 = 0.f, p3 = 0.f;
                #pragma unroll
                for (int j = 0; j < 8; ++j) {
                    float d0 = va0[j] - mu8[j];
                    float d1 = va1[j] - mu8[j];
                    float d2 = va2[j] - mu8[j];
                    float d3 = va3[j] - mu8[j];
                    p0 += d0 * d0 * is8[j];
                    p1 += d1 * d1 * is8[j];
                    p2 += d2 * d2 * is8[j];
                    p3 += d3 * d3 * is8[j];
                }
                p0 = xhalf_sum(p0); p1 = xhalf_sum(p1);
                p2 = xhalf_sum(p2); p3 = xhalf_sum(p3);
                float a0 = kcv - p0, a1 = kcv - p1, a2 = kcv - p2, a3 = kcv - p3;
                float m0 = red_max32(a0), m1 = red_max32(a1);
                float m2 = red_max32(a2), m3 = red_max32(a3);
                float e0 = __expf(a0 - m0), e1 = __expf(a1 - m1);
                float e2 = __expf(a2 - m2), e3 = __expf(a3 - m3);
                float q0 = red_sum32(e0), q1 = red_sum32(e1);
                float q2 = red_sum32(e2), q3 = red_sum32(e3);
                rr0 = (e0 / q0) * fct_s[ia0];
                rr1 = (e1 / q1) * fct_s[ia1];
                rr2 = (e2 / q2) * fct_s[ia2];
                rr3 = (e3 / q3) * fct_s[ia3];
            }

            s0 += (rr0 + rr1) + (rr2 + rr3);
            #pragma unroll
            for (int j = 0; j < 8; ++j) {
                s1[j] += rr0 * va0[j] + rr1 * va1[j] + rr2 * va2[j] + rr3 * va3[j];
                s2[j] += rr0 * va0[j] * va0[j] + rr1 * va1[j] * va1[j]
                       + rr2 * va2[j] * va2[j] + rr3 * va3[j] * va3[j];
            }
            u0 = n0; u1 = n1; u2 = n2; u3 = n3;
        }

        // tail pair: rows k=16 (u0), k=17 (u1)
        {
            const int ia0 = 16 * 16 + wv;
            const int ia1 = 17 * 16 + wv;
            f8v8 va0 = expand8v(u0), va1 = expand8v(u1);
            float rr0, rr1;
            if (t == 0) {
                rr0 = fct_s[ia0] * 0.03125f;
                rr1 = fct_s[ia1] * 0.03125f;
            } else {
                float p0 = 0.f, p1 = 0.f;
                #pragma unroll
                for (int j = 0; j < 8; ++j) {
                    float d0 = va0[j] - mu8[j];
                    float d1 = va1[j] - mu8[j];
                    p0 += d0 * d0 * is8[j];
                    p1 += d1 * d1 * is8[j];
                }
                p0 = xhalf_sum(p0); p1 = xhalf_sum(p1);
                float a0 = kcv - p0, a1 = kcv - p1;
                float m0 = red_max32(a0), m1 = red_max32(a1);
                float e0 = __expf(a0 - m0), e1 = __expf(a1 - m1);
                float q0 = red_sum32(e0), q1 = red_sum32(e1);
                rr0 = (e0 / q0) * fct_s[ia0];
                rr1 = (e1 / q1) * fct_s[ia1];
            }
            s0 += rr0 + rr1;
            #pragma unroll
            for (int j = 0; j < 8; ++j) {
                s1[j] += rr0 * va0[j] + rr1 * va1[j];
                s2[j] += rr0 * va0[j] * va0[j] + rr1 * va1[j] * va1[j];
            }
        }

        // per-wave partials -> LDS (stride 17: 2-way bank alias = free)
        {
            float* dst = &red_s[(wv * 64 + lane) * 17];
            dst[0] = s0;
            #pragma unroll
            for (int j = 0; j < 8; ++j) { dst[1 + j] = s1[j]; dst[9 + j] = s2[j]; }
        }
        __syncthreads();

        // final 16-way reduce + mu/sigma + fused a_out (thread = (c2,q2))
        if (tid < 512) {
            const int c2 = tid >> 4, q2 = tid & 15;
            const int qh2 = q2 >> 3, j2 = q2 & 7;
            float S0 = 0.f, S1 = 0.f, S2 = 0.f;
            #pragma unroll
            for (int wvi = 0; wvi < 16; ++wvi) {
                S0 += red_s[(wvi * 64 + c2) * 17];
                const float* sp = &red_s[(wvi * 64 + qh2 * 32 + c2) * 17];
                S1 += sp[1 + j2];
                S2 += sp[9 + j2];
            }
            float invr = 1.0f / (S0 + EPSV);
            float w0  = S0 * invr;
            float m   = S1 * invr;
            float s2p = S2 * invr;
            float sig = s2p - m * m * (2.0f - w0);   // == sum coeff*(v-mu)^2
            sig = fmaxf(sig + EPSV, 1e-4f);
            float hl = 0.5f * logf(sig);
            mu_s[c2 * 17 + q2]   = m;
            i2ss_s[c2 * 17 + q2] = 1.0f / (2.0f * sig);
            // fused old phase-3: 16-lane DPP row (one c2 per row) sums hl
            float shl = red_sum16(hl);
            if (q2 == 0) {
                float bu  = beta_u[c2];
                float cs  = (16.0f * bu + shl) * S0;
                float arg = LAMBDAV * (beta_a[c2] - cs);
                float ao  = 1.0f / (1.0f + expf(-arg));
                ao = fminf(fmaxf(ao, 1e-4f), 1.0f - 1e-4f);
                aout_s[c2] = ao;
                kc_s[c2]   = logf(ao + EPSV) - shl - 8.0f * LN_2PI;
            }
        }
        __syncthreads();
    }

    // epilogue (fp32): p_out [0,65536) | a_out [65536,69632) | out [69632,139264)
    if (tid < 512) {
        int c2 = tid >> 4, q2 = tid & 15;
        float mu = mu_s[c2 * 17 + q2];
        if (isnan(mu)) mu = 0.f;
        mu = fminf(fmaxf(mu, -10000.f), 10000.f);
        out[(size_t)n * 512 + tid] = mu;
        out[69632 + (size_t)n * 544 + tid] = mu;
        if (tid < 32) {
            float ao = aout_s[tid];
            if (isnan(ao)) ao = 0.5f;
            out[65536 + n * 32 + tid] = ao;
            out[69632 + n * 544 + 512 + tid] = ao;
        }
    }
}

extern "C" void kernel_launch(void* const* d_in, const int* in_sizes, int n_in,
                              void* d_out, int out_size, void* d_ws, size_t ws_size,
                              hipStream_t stream) {
    const float* x  = (const float*)d_in[0];
    const float* w  = (const float*)d_in[1];
    const float* bu = (const float*)d_in[2];
    const float* ba = (const float*)d_in[3];
    float* out = (float*)d_out;
    __hip_bfloat16* v = (__hip_bfloat16*)d_ws;  // 128*288*512 bf16 = 37.7 MB

    conv_v_kernel<<<dim3(576), dim3(256), 0, stream>>>(x, w, v);
    em_routing_kernel<<<dim3(128), dim3(1024), 0, stream>>>(
        x, (const unsigned short*)v, bu, ba, out);
}

// Round 9
// 117.503 us; speedup vs baseline: 2.0888x; 1.7582x over previous
//
#include <hip/hip_runtime.h>
#include <hip/hip_bf16.h>
#include <math.h>

#define EPSV 1e-6f
#define LAMBDAV 1e-3f
#define LN_2PI 1.8378770664093453f

__device__ __forceinline__ float bflo(unsigned int u) {
    union { unsigned int i; float f; } x; x.i = u << 16; return x.f;
}
__device__ __forceinline__ float bfhi(unsigned int u) {
    union { unsigned int i; float f; } x; x.i = u & 0xffff0000u; return x.f;
}
__device__ __forceinline__ unsigned short f2bf(float f) {
    __hip_bfloat16 h = __float2bfloat16(f);
    return *(unsigned short*)&h;
}

typedef __attribute__((ext_vector_type(8))) short s8v;
typedef __attribute__((ext_vector_type(4))) float f4v;
typedef __attribute__((ext_vector_type(2))) int i2v;

// DPP lane-permute move (VALU-latency cross-lane, no LDS pipe).
template<int CTRL>
__device__ __forceinline__ float dpp_mv(float x) {
    return __int_as_float(__builtin_amdgcn_update_dpp(
        0, __float_as_int(x), CTRL, 0xF, 0xF, true));
}
__device__ __forceinline__ float x16_sum(float x) {
#if __has_builtin(__builtin_amdgcn_permlane16_swap)
    i2v r = __builtin_amdgcn_permlane16_swap(__float_as_int(x), __float_as_int(x), false, false);
    return __int_as_float(r.x) + __int_as_float(r.y);
#else
    return x + __int_as_float(__builtin_amdgcn_ds_swizzle(__float_as_int(x), 0x401F));
#endif
}
__device__ __forceinline__ float x16_max(float x) {
#if __has_builtin(__builtin_amdgcn_permlane16_swap)
    i2v r = __builtin_amdgcn_permlane16_swap(__float_as_int(x), __float_as_int(x), false, false);
    return fmaxf(__int_as_float(r.x), __int_as_float(r.y));
#else
    return fmaxf(x, __int_as_float(__builtin_amdgcn_ds_swizzle(__float_as_int(x), 0x401F)));
#endif
}
__device__ __forceinline__ float xhalf_sum(float x) {
#if __has_builtin(__builtin_amdgcn_permlane32_swap)
    i2v r = __builtin_amdgcn_permlane32_swap(__float_as_int(x), __float_as_int(x), false, false);
    return __int_as_float(r.x) + __int_as_float(r.y);
#else
    return x + __shfl_xor(x, 32, 64);
#endif
}
__device__ __forceinline__ float red_max32(float x) {
    x = fmaxf(x, dpp_mv<0xB1>(x));    // quad_perm [1,0,3,2]  (xor 1)
    x = fmaxf(x, dpp_mv<0x4E>(x));    // quad_perm [2,3,0,1]  (xor 2)
    x = fmaxf(x, dpp_mv<0x124>(x));   // row_ror:4
    x = fmaxf(x, dpp_mv<0x128>(x));   // row_ror:8
    return x16_max(x);
}
__device__ __forceinline__ float red_sum32(float x) {
    x += dpp_mv<0xB1>(x);
    x += dpp_mv<0x4E>(x);
    x += dpp_mv<0x124>(x);
    x += dpp_mv<0x128>(x);
    return x16_sum(x);
}
__device__ __forceinline__ float red_sum16(float x) {
    x += dpp_mv<0xB1>(x);
    x += dpp_mv<0x4E>(x);
    x += dpp_mv<0x124>(x);
    x += dpp_mv<0x128>(x);
    return x;
}

// Kernel 1: MFMA conv, M-split: 576 blocks = (i2, cq-half). 30KB LDS/block ->
// ~5 blocks/CU capacity, removes the 288=256+32 two-round quantization.
__global__ __launch_bounds__(256)
void conv_v_kernel(const float* __restrict__ x, const float* __restrict__ w,
                   __hip_bfloat16* __restrict__ vout)
{
    __shared__ unsigned short wb[256 * 40];  // [cq_local][p pad40]
    __shared__ unsigned short pb[128 * 40];  // [n][p pad40]

    const int bid = blockIdx.x;
    const int i2  = bid >> 1;
    const int mh  = bid & 1;                 // cq half: [mh*256, mh*256+256)
    const int tid = threadIdx.x;

    // zero k=16..31 padding (mfma reads k<32)
    for (int u = tid; u < 256 * 8; u += 256) {
        int r = u >> 3, j = u & 7;
        *(unsigned int*)&wb[r * 40 + 16 + j * 2] = 0;
    }
    for (int u = tid; u < 128 * 8; u += 256) {
        int r = u >> 3, j = u & 7;
        *(unsigned int*)&pb[r * 40 + 16 + j * 2] = 0;
    }
    // stage w[i2][c][p][q] fp32 -> wb[(c_local*16+q)][p] bf16 for c_local 0..15
    #pragma unroll 4
    for (int u = 0; u < 16; ++u) {
        int idx = u * 256 + tid;               // cl*256 + p*16 + q
        int cl = idx >> 8, p = (idx >> 4) & 15, q = idx & 15;
        wb[(cl * 16 + q) * 40 + p] = f2bf(w[(size_t)i2 * 8192 + mh * 4096 + idx]);
    }
    // fused gather: pb[nn][p] from x via reference reshape scramble
    #pragma unroll
    for (int u = 0; u < 8; ++u) {
        int idx = u * 256 + tid;               // nn*16 + p
        int nn = idx >> 4, p = idx & 15;
        int e  = i2 * 16 + p;
        int k2 = e >> 9, c2 = e & 511;
        int f  = k2 * 544 + c2;
        int ci = f / 9, kk = f - ci * 9;
        int bi = nn >> 6, oi = (nn >> 3) & 7, oj = nn & 7;
        int row = 2 * oi + kk / 3 - 1;
        int col = 2 * oj + (kk - (kk / 3) * 3) - 1;
        float val = 0.f;
        if ((unsigned)row < 16u && (unsigned)col < 16u)
            val = x[((bi * 16 + row) * 16 + col) * 544 + ci];
        pb[nn * 40 + p] = f2bf(val);
    }
    __syncthreads();

    const int lane = tid & 63;
    const int wv   = tid >> 6;
    const int l16  = lane & 15;
    const int quad = lane >> 4;
    const int cq0l = wv * 64;                  // local cq base of this wave

    s8v afrag[4], bfrag[8];
    #pragma unroll
    for (int mt = 0; mt < 4; ++mt)
        afrag[mt] = *(const s8v*)&wb[(cq0l + mt * 16 + l16) * 40 + quad * 8];
    #pragma unroll
    for (int nt = 0; nt < 8; ++nt)
        bfrag[nt] = *(const s8v*)&pb[(nt * 16 + l16) * 40 + quad * 8];

    #pragma unroll
    for (int nt = 0; nt < 8; ++nt) {
        const int nl = nt * 16 + l16;
        #pragma unroll
        for (int mt = 0; mt < 4; ++mt) {
            f4v acc = {0.f, 0.f, 0.f, 0.f};
            acc = __builtin_amdgcn_mfma_f32_16x16x32_bf16(afrag[mt], bfrag[nt], acc, 0, 0, 0);
            int cq = mh * 256 + cq0l + mt * 16 + quad * 4;
            unsigned int lo = f2bf(acc[0]) | ((unsigned int)f2bf(acc[1]) << 16);
            unsigned int hi = f2bf(acc[2]) | ((unsigned int)f2bf(acc[3]) << 16);
            uint2 pk; pk.x = lo; pk.y = hi;
            *(uint2*)((unsigned short*)vout + ((size_t)nl * 288 + i2) * 512 + cq) = pk;
        }
    }
}

// Kernel 2: one EM sweep (iteration t), grid 256 = (n, h). h=0 sweeps rows
// k=0..9 (5 pairs), h=1 rows k=10..17 (4 pairs) -- both are pure R4-style
// pair-loops (no tail block / no else-prefetch: that structure spilled ~30-50
// regs/thread in R3/R5-R7). Partial sums go to this block's OWN gpart slot
// with plain stores; ordering/visibility via stream kernel boundaries.
// No fences, no atomics (R3's AGENT-acquire flushed L2: FETCH 3x).
__global__ __launch_bounds__(1024, 4)
void em_sweep_kernel(const float* __restrict__ x,
                     const unsigned short* __restrict__ v,   // [n][i][cq] bf16
                     const float* __restrict__ beta_u,
                     const float* __restrict__ beta_a,
                     float* __restrict__ gpart,              // [t][n][h][1088]
                     const int t)
{
    __shared__ float fct_s[288];            // a/(a+eps)
    __shared__ float red_s[16 * 64 * 17];   // [wave][lane][s0|s1[8]|s2[8]]
    __shared__ float mu_s[32 * 17];
    __shared__ float i2ss_s[32 * 17];
    __shared__ float kc_s[32];

    const int bid = blockIdx.x;
    const int n   = bid & 127;
    const int h   = bid >> 7;
    const int tid = threadIdx.x;
    const int bi = n >> 6, oi = (n >> 3) & 7, oj = n & 7;

    if (tid < 288) {
        int k2 = tid >> 5;
        int c2 = 512 + (tid & 31);
        int f  = k2 * 544 + c2;
        int ci = f / 9;
        int kk = f - ci * 9;
        int row = 2 * oi + kk / 3 - 1;
        int col = 2 * oj + (kk - (kk / 3) * 3) - 1;
        float a = 0.f;
        if ((unsigned)row < 16u && (unsigned)col < 16u)
            a = x[((bi * 16 + row) * 16 + col) * 544 + ci];
        fct_s[tid] = a / (a + EPSV);   // sum_c r*a == a -> rr = softmax * fct
    }

    // finalize previous iteration's stats from both halves (t>0)
    if (t > 0 && tid < 512) {
        const int c2 = tid >> 4, q2 = tid & 15;
        const float* pa = gpart + ((size_t)(t - 1) * 128 + n) * 2 * 1088;
        float S1 = pa[tid] + pa[1088 + tid];
        float S2 = pa[512 + tid] + pa[1088 + 512 + tid];
        float S0 = pa[1024 + c2] + pa[1088 + 1024 + c2];
        float invr = 1.0f / (S0 + EPSV);
        float w0  = S0 * invr;
        float m   = S1 * invr;
        float s2p = S2 * invr;
        float sig = s2p - m * m * (2.0f - w0);   // == sum coeff*(v-mu)^2
        sig = fmaxf(sig + EPSV, 1e-4f);
        float hl = 0.5f * logf(sig);
        mu_s[c2 * 17 + q2]   = m;
        i2ss_s[c2 * 17 + q2] = 1.0f / (2.0f * sig);
        float shl = red_sum16(hl);
        if (q2 == 0) {
            float bu  = beta_u[c2];
            float cs  = (16.0f * bu + shl) * S0;
            float arg = LAMBDAV * (beta_a[c2] - cs);
            float ao  = 1.0f / (1.0f + expf(-arg));
            ao = fminf(fmaxf(ao, 1e-4f), 1.0f - 1e-4f);
            kc_s[c2]  = logf(ao + EPSV) - shl - 8.0f * LN_2PI;
        }
    }
    __syncthreads();

    const unsigned short* vb = v + (size_t)n * 288 * 512;
    const int wv   = tid >> 6;      // wave 0..15
    const int lane = tid & 63;
    const int c    = lane & 31;
    const int qh   = lane >> 5;     // q-half 0/1
    const int qb   = qh * 8;
    const unsigned short* base = vb + c * 16 + qb;

    float mu8[8], is8[8], kcv = 0.f;
    if (t > 0) {
        #pragma unroll
        for (int j = 0; j < 8; ++j) {
            mu8[j] = mu_s[c * 17 + qb + j];
            is8[j] = i2ss_s[c * 17 + qb + j];
        }
        kcv = kc_s[c];
    }

    float s0 = 0.f, s1[8], s2[8];
    #pragma unroll
    for (int j = 0; j < 8; ++j) { s1[j] = 0.f; s2[j] = 0.f; }

    const int kofs  = h * 10;        // h=0: k 0..9, h=1: k 10..17
    const int npair = 5 - h;         // 5 or 4 pairs, no tail

    // prefetch pair 0
    uint4 ua = *(const uint4*)(base + (size_t)((kofs + 0) * 16 + wv) * 512);
    uint4 ub = *(const uint4*)(base + (size_t)((kofs + 1) * 16 + wv) * 512);

    for (int kp = 0; kp < npair; ++kp) {
        const int ia = (kofs + 2 * kp) * 16 + wv;
        const int ib = ia + 16;
        uint4 una = ua, unb = ub;
        if (kp + 1 < npair) {   // issue next pair before the compute chain
            una = *(const uint4*)(base + (size_t)(ia + 32) * 512);
            unb = *(const uint4*)(base + (size_t)(ia + 48) * 512);
        }
        float va[8], vvb[8];
        va[0] = bflo(ua.x); va[1] = bfhi(ua.x);
        va[2] = bflo(ua.y); va[3] = bfhi(ua.y);
        va[4] = bflo(ua.z); va[5] = bfhi(ua.z);
        va[6] = bflo(ua.w); va[7] = bfhi(ua.w);
        vvb[0] = bflo(ub.x); vvb[1] = bfhi(ub.x);
        vvb[2] = bflo(ub.y); vvb[3] = bfhi(ub.y);
        vvb[4] = bflo(ub.z); vvb[5] = bfhi(ub.z);
        vvb[6] = bflo(ub.w); vvb[7] = bfhi(ub.w);

        float rra, rrb;
        if (t == 0) {
            rra = fct_s[ia] * 0.03125f;
            rrb = fct_s[ib] * 0.03125f;
        } else {
            float pa = 0.f, pb2 = 0.f;
            #pragma unroll
            for (int j = 0; j < 8; ++j) {
                float da = va[j] - mu8[j];
                float db = vvb[j] - mu8[j];
                pa  += da * da * is8[j];
                pb2 += db * db * is8[j];
            }
            pa  = xhalf_sum(pa);      // combine q-halves (xor32, VALU)
            pb2 = xhalf_sum(pb2);
            float acca = kcv - pa;
            float accb = kcv - pb2;
            float mxa = red_max32(acca);
            float mxb = red_max32(accb);
            float ea = __expf(acca - mxa);
            float eb = __expf(accb - mxb);
            float sa = red_sum32(ea);
            float sb = red_sum32(eb);
            rra = (ea / sa) * fct_s[ia];
            rrb = (eb / sb) * fct_s[ib];
        }

        s0 += rra + rrb;
        #pragma unroll
        for (int j = 0; j < 8; ++j) {
            s1[j] += rra * va[j] + rrb * vvb[j];
            s2[j] += rra * va[j] * va[j] + rrb * vvb[j] * vvb[j];
        }
        ua = una; ub = unb;
    }

    // per-wave partials -> LDS (stride 17: 2-way bank alias = free)
    {
        float* dst = &red_s[(wv * 64 + lane) * 17];
        dst[0] = s0;
        #pragma unroll
        for (int j = 0; j < 8; ++j) { dst[1 + j] = s1[j]; dst[9 + j] = s2[j]; }
    }
    __syncthreads();

    // final 16-way reduce -> this block's own gpart slot (plain stores)
    if (tid < 512) {
        const int c2 = tid >> 4, q2 = tid & 15;
        const int qh2 = q2 >> 3, j2 = q2 & 7;
        float S0 = 0.f, S1 = 0.f, S2 = 0.f;
        #pragma unroll
        for (int wvi = 0; wvi < 16; ++wvi) {
            S0 += red_s[(wvi * 64 + c2) * 17];
            const float* sp = &red_s[(wvi * 64 + qh2 * 32 + c2) * 17];
            S1 += sp[1 + j2];
            S2 += sp[9 + j2];
        }
        float* po = gpart + (((size_t)t * 128 + n) * 2 + h) * 1088;
        po[tid] = S1;
        po[512 + tid] = S2;
        if (q2 == 0) po[1024 + c2] = S0;
    }
}

// Kernel 3: epilogue — finalize t=2 stats, write p_out / a_out / out.
__global__ __launch_bounds__(512)
void em_final_kernel(const float* __restrict__ gpart,
                     const float* __restrict__ beta_u,
                     const float* __restrict__ beta_a,
                     float* __restrict__ out)
{
    __shared__ float aout_s[32];
    const int n   = blockIdx.x;
    const int tid = threadIdx.x;           // 512
    const int c2 = tid >> 4, q2 = tid & 15;

    const float* pa = gpart + ((size_t)2 * 128 + n) * 2 * 1088;
    float S1 = pa[tid] + pa[1088 + tid];
    float S2 = pa[512 + tid] + pa[1088 + 512 + tid];
    float S0 = pa[1024 + c2] + pa[1088 + 1024 + c2];
    float invr = 1.0f / (S0 + EPSV);
    float w0  = S0 * invr;
    float m   = S1 * invr;
    float s2p = S2 * invr;
    float sig = s2p - m * m * (2.0f - w0);
    sig = fmaxf(sig + EPSV, 1e-4f);
    float hl = 0.5f * logf(sig);
    float shl = red_sum16(hl);
    if (q2 == 0) {
        float bu  = beta_u[c2];
        float cs  = (16.0f * bu + shl) * S0;
        float arg = LAMBDAV * (beta_a[c2] - cs);
        float ao  = 1.0f / (1.0f + expf(-arg));
        ao = fminf(fmaxf(ao, 1e-4f), 1.0f - 1e-4f);
        if (isnan(ao)) ao = 0.5f;
        aout_s[c2] = ao;
    }
    float mu = m;
    if (isnan(mu)) mu = 0.f;
    mu = fminf(fmaxf(mu, -10000.f), 10000.f);
    out[(size_t)n * 512 + tid] = mu;
    out[69632 + (size_t)n * 544 + tid] = mu;
    __syncthreads();
    if (tid < 32) {
        float ao = aout_s[tid];
        out[65536 + n * 32 + tid] = ao;
        out[69632 + n * 544 + 512 + tid] = ao;
    }
}

extern "C" void kernel_launch(void* const* d_in, const int* in_sizes, int n_in,
                              void* d_out, int out_size, void* d_ws, size_t ws_size,
                              hipStream_t stream) {
    const float* x  = (const float*)d_in[0];
    const float* w  = (const float*)d_in[1];
    const float* bu = (const float*)d_in[2];
    const float* ba = (const float*)d_in[3];
    float* out = (float*)d_out;
    __hip_bfloat16* v = (__hip_bfloat16*)d_ws;               // 37.7 MB
    float* gpart = (float*)((char*)d_ws + (40u << 20));      // [3][128][2][1088]

    conv_v_kernel<<<dim3(576), dim3(256), 0, stream>>>(x, w, v);
    em_sweep_kernel<<<dim3(256), dim3(1024), 0, stream>>>(
        x, (const unsigned short*)v, bu, ba, gpart, 0);
    em_sweep_kernel<<<dim3(256), dim3(1024), 0, stream>>>(
        x, (const unsigned short*)v, bu, ba, gpart, 1);
    em_sweep_kernel<<<dim3(256), dim3(1024), 0, stream>>>(
        x, (const unsigned short*)v, bu, ba, gpart, 2);
    em_final_kernel<<<dim3(128), dim3(512), 0, stream>>>(gpart, bu, ba, out);
}

// Round 10
// 117.101 us; speedup vs baseline: 2.0960x; 1.0034x over previous
//
#include <hip/hip_runtime.h>
#include <hip/hip_bf16.h>
#include <math.h>

#define EPSV 1e-6f
#define LAMBDAV 1e-3f
#define LN_2PI 1.8378770664093453f

__device__ __forceinline__ float bflo(unsigned int u) {
    union { unsigned int i; float f; } x; x.i = u << 16; return x.f;
}
__device__ __forceinline__ float bfhi(unsigned int u) {
    union { unsigned int i; float f; } x; x.i = u & 0xffff0000u; return x.f;
}
__device__ __forceinline__ unsigned short f2bf(float f) {
    __hip_bfloat16 h = __float2bfloat16(f);
    return *(unsigned short*)&h;
}

typedef __attribute__((ext_vector_type(8))) short s8v;
typedef __attribute__((ext_vector_type(4))) float f4v;
typedef __attribute__((ext_vector_type(2))) int i2v;

// DPP lane-permute move (VALU-latency cross-lane, no LDS pipe).
template<int CTRL>
__device__ __forceinline__ float dpp_mv(float x) {
    return __int_as_float(__builtin_amdgcn_update_dpp(
        0, __float_as_int(x), CTRL, 0xF, 0xF, true));
}
__device__ __forceinline__ float x16_sum(float x) {
#if __has_builtin(__builtin_amdgcn_permlane16_swap)
    i2v r = __builtin_amdgcn_permlane16_swap(__float_as_int(x), __float_as_int(x), false, false);
    return __int_as_float(r.x) + __int_as_float(r.y);
#else
    return x + __int_as_float(__builtin_amdgcn_ds_swizzle(__float_as_int(x), 0x401F));
#endif
}
__device__ __forceinline__ float x16_max(float x) {
#if __has_builtin(__builtin_amdgcn_permlane16_swap)
    i2v r = __builtin_amdgcn_permlane16_swap(__float_as_int(x), __float_as_int(x), false, false);
    return fmaxf(__int_as_float(r.x), __int_as_float(r.y));
#else
    return fmaxf(x, __int_as_float(__builtin_amdgcn_ds_swizzle(__float_as_int(x), 0x401F)));
#endif
}
__device__ __forceinline__ float xhalf_sum(float x) {
#if __has_builtin(__builtin_amdgcn_permlane32_swap)
    i2v r = __builtin_amdgcn_permlane32_swap(__float_as_int(x), __float_as_int(x), false, false);
    return __int_as_float(r.x) + __int_as_float(r.y);
#else
    return x + __shfl_xor(x, 32, 64);
#endif
}
__device__ __forceinline__ float red_max32(float x) {
    x = fmaxf(x, dpp_mv<0xB1>(x));    // quad_perm [1,0,3,2]  (xor 1)
    x = fmaxf(x, dpp_mv<0x4E>(x));    // quad_perm [2,3,0,1]  (xor 2)
    x = fmaxf(x, dpp_mv<0x124>(x));   // row_ror:4
    x = fmaxf(x, dpp_mv<0x128>(x));   // row_ror:8
    return x16_max(x);
}
__device__ __forceinline__ float red_sum32(float x) {
    x += dpp_mv<0xB1>(x);
    x += dpp_mv<0x4E>(x);
    x += dpp_mv<0x124>(x);
    x += dpp_mv<0x128>(x);
    return x16_sum(x);
}
__device__ __forceinline__ float red_sum16(float x) {
    x += dpp_mv<0xB1>(x);
    x += dpp_mv<0x4E>(x);
    x += dpp_mv<0x124>(x);
    x += dpp_mv<0x128>(x);
    return x;
}

// Kernel 1: MFMA conv, M-split: 576 blocks = (i2, cq-half). 30KB LDS/block ->
// ~5 blocks/CU capacity, removes the 288=256+32 two-round quantization.
__global__ __launch_bounds__(256)
void conv_v_kernel(const float* __restrict__ x, const float* __restrict__ w,
                   __hip_bfloat16* __restrict__ vout)
{
    __shared__ unsigned short wb[256 * 40];  // [cq_local][p pad40]
    __shared__ unsigned short pb[128 * 40];  // [n][p pad40]

    const int bid = blockIdx.x;
    const int i2  = bid >> 1;
    const int mh  = bid & 1;                 // cq half: [mh*256, mh*256+256)
    const int tid = threadIdx.x;

    // zero k=16..31 padding (mfma reads k<32)
    for (int u = tid; u < 256 * 8; u += 256) {
        int r = u >> 3, j = u & 7;
        *(unsigned int*)&wb[r * 40 + 16 + j * 2] = 0;
    }
    for (int u = tid; u < 128 * 8; u += 256) {
        int r = u >> 3, j = u & 7;
        *(unsigned int*)&pb[r * 40 + 16 + j * 2] = 0;
    }
    // stage w[i2][c][p][q] fp32 -> wb[(c_local*16+q)][p] bf16 for c_local 0..15
    #pragma unroll 4
    for (int u = 0; u < 16; ++u) {
        int idx = u * 256 + tid;               // cl*256 + p*16 + q
        int cl = idx >> 8, p = (idx >> 4) & 15, q = idx & 15;
        wb[(cl * 16 + q) * 40 + p] = f2bf(w[(size_t)i2 * 8192 + mh * 4096 + idx]);
    }
    // fused gather: pb[nn][p] from x via reference reshape scramble
    #pragma unroll
    for (int u = 0; u < 8; ++u) {
        int idx = u * 256 + tid;               // nn*16 + p
        int nn = idx >> 4, p = idx & 15;
        int e  = i2 * 16 + p;
        int k2 = e >> 9, c2 = e & 511;
        int f  = k2 * 544 + c2;
        int ci = f / 9, kk = f - ci * 9;
        int bi = nn >> 6, oi = (nn >> 3) & 7, oj = nn & 7;
        int row = 2 * oi + kk / 3 - 1;
        int col = 2 * oj + (kk - (kk / 3) * 3) - 1;
        float val = 0.f;
        if ((unsigned)row < 16u && (unsigned)col < 16u)
            val = x[((bi * 16 + row) * 16 + col) * 544 + ci];
        pb[nn * 40 + p] = f2bf(val);
    }
    __syncthreads();

    const int lane = tid & 63;
    const int wv   = tid >> 6;
    const int l16  = lane & 15;
    const int quad = lane >> 4;
    const int cq0l = wv * 64;                  // local cq base of this wave

    s8v afrag[4], bfrag[8];
    #pragma unroll
    for (int mt = 0; mt < 4; ++mt)
        afrag[mt] = *(const s8v*)&wb[(cq0l + mt * 16 + l16) * 40 + quad * 8];
    #pragma unroll
    for (int nt = 0; nt < 8; ++nt)
        bfrag[nt] = *(const s8v*)&pb[(nt * 16 + l16) * 40 + quad * 8];

    #pragma unroll
    for (int nt = 0; nt < 8; ++nt) {
        const int nl = nt * 16 + l16;
        #pragma unroll
        for (int mt = 0; mt < 4; ++mt) {
            f4v acc = {0.f, 0.f, 0.f, 0.f};
            acc = __builtin_amdgcn_mfma_f32_16x16x32_bf16(afrag[mt], bfrag[nt], acc, 0, 0, 0);
            int cq = mh * 256 + cq0l + mt * 16 + quad * 4;
            unsigned int lo = f2bf(acc[0]) | ((unsigned int)f2bf(acc[1]) << 16);
            unsigned int hi = f2bf(acc[2]) | ((unsigned int)f2bf(acc[3]) << 16);
            uint2 pk; pk.x = lo; pk.y = hi;
            *(uint2*)((unsigned short*)vout + ((size_t)nl * 288 + i2) * 512 + cq) = pk;
        }
    }
}

// Kernel 2: one EM sweep (iteration t), grid 768 = (n, h in 0..5). Block =
// 512 threads = 8 waves; each wave does exactly 3 row-pairs (uniform clean
// loop -- the tail/else-prefetch structures that spilled in R3/R5-R7 stay
// banned). ~41 KB LDS -> 3 blocks/CU co-resident (24 waves/CU vs R9's 16),
// so a __syncthreads convoy idles only 1/3 of the CU. Partials to this
// block's own gpart slot; visibility via stream kernel boundaries.
__global__ __launch_bounds__(512)
void em_sweep_kernel(const float* __restrict__ x,
                     const unsigned short* __restrict__ v,   // [n][i][cq] bf16
                     const float* __restrict__ beta_u,
                     const float* __restrict__ beta_a,
                     float* __restrict__ gpart,              // [t][n][6][1088]
                     const int t)
{
    __shared__ float fct_s[288];            // a/(a+eps)
    __shared__ float red_s[8 * 64 * 17];    // [wave][lane][s0|s1[8]|s2[8]]
    __shared__ float mu_s[32 * 17];
    __shared__ float i2ss_s[32 * 17];
    __shared__ float kc_s[32];

    const int bid = blockIdx.x;
    const int n   = bid & 127;
    const int h   = bid >> 7;               // 0..5, rows [h*48, h*48+48)
    const int tid = threadIdx.x;
    const int bi = n >> 6, oi = (n >> 3) & 7, oj = n & 7;

    if (tid < 288) {
        int k2 = tid >> 5;
        int c2 = 512 + (tid & 31);
        int f  = k2 * 544 + c2;
        int ci = f / 9;
        int kk = f - ci * 9;
        int row = 2 * oi + kk / 3 - 1;
        int col = 2 * oj + (kk - (kk / 3) * 3) - 1;
        float a = 0.f;
        if ((unsigned)row < 16u && (unsigned)col < 16u)
            a = x[((bi * 16 + row) * 16 + col) * 544 + ci];
        fct_s[tid] = a / (a + EPSV);   // sum_c r*a == a -> rr = softmax * fct
    }

    // finalize previous iteration's stats from all 6 slices (t>0)
    if (t > 0) {
        const int c2 = tid >> 4, q2 = tid & 15;
        const float* pa = gpart + ((size_t)(t - 1) * 128 + n) * 6 * 1088;
        float S1 = 0.f, S2 = 0.f, S0 = 0.f;
        #pragma unroll
        for (int j = 0; j < 6; ++j) {
            S1 += pa[j * 1088 + tid];
            S2 += pa[j * 1088 + 512 + tid];
            S0 += pa[j * 1088 + 1024 + c2];
        }
        float invr = 1.0f / (S0 + EPSV);
        float w0  = S0 * invr;
        float m   = S1 * invr;
        float s2p = S2 * invr;
        float sig = s2p - m * m * (2.0f - w0);   // == sum coeff*(v-mu)^2
        sig = fmaxf(sig + EPSV, 1e-4f);
        float hl = 0.5f * logf(sig);
        mu_s[c2 * 17 + q2]   = m;
        i2ss_s[c2 * 17 + q2] = 1.0f / (2.0f * sig);
        float shl = red_sum16(hl);
        if (q2 == 0) {
            float bu  = beta_u[c2];
            float cs  = (16.0f * bu + shl) * S0;
            float arg = LAMBDAV * (beta_a[c2] - cs);
            float ao  = 1.0f / (1.0f + expf(-arg));
            ao = fminf(fmaxf(ao, 1e-4f), 1.0f - 1e-4f);
            kc_s[c2]  = logf(ao + EPSV) - shl - 8.0f * LN_2PI;
        }
    }
    __syncthreads();

    const unsigned short* vb = v + (size_t)n * 288 * 512;
    const int wv   = tid >> 6;      // wave 0..7
    const int lane = tid & 63;
    const int c    = lane & 31;
    const int qh   = lane >> 5;     // q-half 0/1
    const int qb   = qh * 8;
    const unsigned short* base = vb + c * 16 + qb;

    float mu8[8], is8[8], kcv = 0.f;
    if (t > 0) {
        #pragma unroll
        for (int j = 0; j < 8; ++j) {
            mu8[j] = mu_s[c * 17 + qb + j];
            is8[j] = i2ss_s[c * 17 + qb + j];
        }
        kcv = kc_s[c];
    }

    float s0 = 0.f, s1[8], s2[8];
    #pragma unroll
    for (int j = 0; j < 8; ++j) { s1[j] = 0.f; s2[j] = 0.f; }

    const int kofs = h * 48;         // rows kofs + kp*16 + {wv, wv+8}, kp<3

    // prefetch pair 0
    uint4 ua = *(const uint4*)(base + (size_t)(kofs + 0 + wv) * 512);
    uint4 ub = *(const uint4*)(base + (size_t)(kofs + 8 + wv) * 512);

    #pragma unroll
    for (int kp = 0; kp < 3; ++kp) {
        const int ia = kofs + kp * 16 + wv;
        const int ib = ia + 8;
        uint4 una = ua, unb = ub;
        if (kp < 2) {   // issue next pair before the compute chain
            una = *(const uint4*)(base + (size_t)(ia + 16) * 512);
            unb = *(const uint4*)(base + (size_t)(ia + 24) * 512);
        }
        float va[8], vvb[8];
        va[0] = bflo(ua.x); va[1] = bfhi(ua.x);
        va[2] = bflo(ua.y); va[3] = bfhi(ua.y);
        va[4] = bflo(ua.z); va[5] = bfhi(ua.z);
        va[6] = bflo(ua.w); va[7] = bfhi(ua.w);
        vvb[0] = bflo(ub.x); vvb[1] = bfhi(ub.x);
        vvb[2] = bflo(ub.y); vvb[3] = bfhi(ub.y);
        vvb[4] = bflo(ub.z); vvb[5] = bfhi(ub.z);
        vvb[6] = bflo(ub.w); vvb[7] = bfhi(ub.w);

        float rra, rrb;
        if (t == 0) {
            rra = fct_s[ia] * 0.03125f;
            rrb = fct_s[ib] * 0.03125f;
        } else {
            float pa = 0.f, pb2 = 0.f;
            #pragma unroll
            for (int j = 0; j < 8; ++j) {
                float da = va[j] - mu8[j];
                float db = vvb[j] - mu8[j];
                pa  += da * da * is8[j];
                pb2 += db * db * is8[j];
            }
            pa  = xhalf_sum(pa);      // combine q-halves (xor32, VALU)
            pb2 = xhalf_sum(pb2);
            float acca = kcv - pa;
            float accb = kcv - pb2;
            float mxa = red_max32(acca);
            float mxb = red_max32(accb);
            float ea = __expf(acca - mxa);
            float eb = __expf(accb - mxb);
            float sa = red_sum32(ea);
            float sb = red_sum32(eb);
            rra = (ea / sa) * fct_s[ia];
            rrb = (eb / sb) * fct_s[ib];
        }

        s0 += rra + rrb;
        #pragma unroll
        for (int j = 0; j < 8; ++j) {
            s1[j] += rra * va[j] + rrb * vvb[j];
            s2[j] += rra * va[j] * va[j] + rrb * vvb[j] * vvb[j];
        }
        ua = una; ub = unb;
    }

    // per-wave partials -> LDS (stride 17: 2-way bank alias = free)
    {
        float* dst = &red_s[(wv * 64 + lane) * 17];
        dst[0] = s0;
        #pragma unroll
        for (int j = 0; j < 8; ++j) { dst[1 + j] = s1[j]; dst[9 + j] = s2[j]; }
    }
    __syncthreads();

    // final 8-way reduce -> this block's own gpart slot (plain stores)
    {
        const int c2 = tid >> 4, q2 = tid & 15;
        const int qh2 = q2 >> 3, j2 = q2 & 7;
        float S0 = 0.f, S1 = 0.f, S2 = 0.f;
        #pragma unroll
        for (int wvi = 0; wvi < 8; ++wvi) {
            S0 += red_s[(wvi * 64 + c2) * 17];
            const float* sp = &red_s[(wvi * 64 + qh2 * 32 + c2) * 17];
            S1 += sp[1 + j2];
            S2 += sp[9 + j2];
        }
        float* po = gpart + (((size_t)t * 128 + n) * 6 + h) * 1088;
        po[tid] = S1;
        po[512 + tid] = S2;
        if (q2 == 0) po[1024 + c2] = S0;
    }
}

// Kernel 3: epilogue — finalize t=2 stats, write p_out / a_out / out.
__global__ __launch_bounds__(512)
void em_final_kernel(const float* __restrict__ gpart,
                     const float* __restrict__ beta_u,
                     const float* __restrict__ beta_a,
                     float* __restrict__ out)
{
    __shared__ float aout_s[32];
    const int n   = blockIdx.x;
    const int tid = threadIdx.x;           // 512
    const int c2 = tid >> 4, q2 = tid & 15;

    const float* pa = gpart + ((size_t)2 * 128 + n) * 6 * 1088;
    float S1 = 0.f, S2 = 0.f, S0 = 0.f;
    #pragma unroll
    for (int j = 0; j < 6; ++j) {
        S1 += pa[j * 1088 + tid];
        S2 += pa[j * 1088 + 512 + tid];
        S0 += pa[j * 1088 + 1024 + c2];
    }
    float invr = 1.0f / (S0 + EPSV);
    float w0  = S0 * invr;
    float m   = S1 * invr;
    float s2p = S2 * invr;
    float sig = s2p - m * m * (2.0f - w0);
    sig = fmaxf(sig + EPSV, 1e-4f);
    float hl = 0.5f * logf(sig);
    float shl = red_sum16(hl);
    if (q2 == 0) {
        float bu  = beta_u[c2];
        float cs  = (16.0f * bu + shl) * S0;
        float arg = LAMBDAV * (beta_a[c2] - cs);
        float ao  = 1.0f / (1.0f + expf(-arg));
        ao = fminf(fmaxf(ao, 1e-4f), 1.0f - 1e-4f);
        if (isnan(ao)) ao = 0.5f;
        aout_s[c2] = ao;
    }
    float mu = m;
    if (isnan(mu)) mu = 0.f;
    mu = fminf(fmaxf(mu, -10000.f), 10000.f);
    out[(size_t)n * 512 + tid] = mu;
    out[69632 + (size_t)n * 544 + tid] = mu;
    __syncthreads();
    if (tid < 32) {
        float ao = aout_s[tid];
        out[65536 + n * 32 + tid] = ao;
        out[69632 + n * 544 + 512 + tid] = ao;
    }
}

extern "C" void kernel_launch(void* const* d_in, const int* in_sizes, int n_in,
                              void* d_out, int out_size, void* d_ws, size_t ws_size,
                              hipStream_t stream) {
    const float* x  = (const float*)d_in[0];
    const float* w  = (const float*)d_in[1];
    const float* bu = (const float*)d_in[2];
    const float* ba = (const float*)d_in[3];
    float* out = (float*)d_out;
    __hip_bfloat16* v = (__hip_bfloat16*)d_ws;               // 37.7 MB
    float* gpart = (float*)((char*)d_ws + (40u << 20));      // [3][128][6][1088]

    conv_v_kernel<<<dim3(576), dim3(256), 0, stream>>>(x, w, v);
    em_sweep_kernel<<<dim3(768), dim3(512), 0, stream>>>(
        x, (const unsigned short*)v, bu, ba, gpart, 0);
    em_sweep_kernel<<<dim3(768), dim3(512), 0, stream>>>(
        x, (const unsigned short*)v, bu, ba, gpart, 1);
    em_sweep_kernel<<<dim3(768), dim3(512), 0, stream>>>(
        x, (const unsigned short*)v, bu, ba, gpart, 2);
    em_final_kernel<<<dim3(128), dim3(512), 0, stream>>>(gpart, bu, ba, out);
}

// Round 12
// 112.127 us; speedup vs baseline: 2.1890x; 1.0444x over previous
//
#include <hip/hip_runtime.h>
#include <hip/hip_bf16.h>
#include <math.h>

#define EPSV 1e-6f
#define LAMBDAV 1e-3f
#define LN_2PI 1.8378770664093453f

__device__ __forceinline__ float bflo(unsigned int u) {
    union { unsigned int i; float f; } x; x.i = u << 16; return x.f;
}
__device__ __forceinline__ float bfhi(unsigned int u) {
    union { unsigned int i; float f; } x; x.i = u & 0xffff0000u; return x.f;
}
__device__ __forceinline__ unsigned short f2bf(float f) {
    __hip_bfloat16 h = __float2bfloat16(f);
    return *(unsigned short*)&h;
}

typedef __attribute__((ext_vector_type(8))) short s8v;
typedef __attribute__((ext_vector_type(4))) float f4v;
typedef __attribute__((ext_vector_type(2))) int i2v;

// DPP lane-permute move (VALU-latency cross-lane, no LDS pipe).
template<int CTRL>
__device__ __forceinline__ float dpp_mv(float x) {
    return __int_as_float(__builtin_amdgcn_update_dpp(
        0, __float_as_int(x), CTRL, 0xF, 0xF, true));
}
__device__ __forceinline__ float x16_sum(float x) {
#if __has_builtin(__builtin_amdgcn_permlane16_swap)
    i2v r = __builtin_amdgcn_permlane16_swap(__float_as_int(x), __float_as_int(x), false, false);
    return __int_as_float(r.x) + __int_as_float(r.y);
#else
    return x + __int_as_float(__builtin_amdgcn_ds_swizzle(__float_as_int(x), 0x401F));
#endif
}
__device__ __forceinline__ float x16_max(float x) {
#if __has_builtin(__builtin_amdgcn_permlane16_swap)
    i2v r = __builtin_amdgcn_permlane16_swap(__float_as_int(x), __float_as_int(x), false, false);
    return fmaxf(__int_as_float(r.x), __int_as_float(r.y));
#else
    return fmaxf(x, __int_as_float(__builtin_amdgcn_ds_swizzle(__float_as_int(x), 0x401F)));
#endif
}
__device__ __forceinline__ float xhalf_sum(float x) {
#if __has_builtin(__builtin_amdgcn_permlane32_swap)
    i2v r = __builtin_amdgcn_permlane32_swap(__float_as_int(x), __float_as_int(x), false, false);
    return __int_as_float(r.x) + __int_as_float(r.y);
#else
    return x + __shfl_xor(x, 32, 64);
#endif
}
__device__ __forceinline__ float red_max32(float x) {
    x = fmaxf(x, dpp_mv<0xB1>(x));    // quad_perm [1,0,3,2]  (xor 1)
    x = fmaxf(x, dpp_mv<0x4E>(x));    // quad_perm [2,3,0,1]  (xor 2)
    x = fmaxf(x, dpp_mv<0x124>(x));   // row_ror:4
    x = fmaxf(x, dpp_mv<0x128>(x));   // row_ror:8
    return x16_max(x);
}
__device__ __forceinline__ float red_sum32(float x) {
    x += dpp_mv<0xB1>(x);
    x += dpp_mv<0x4E>(x);
    x += dpp_mv<0x124>(x);
    x += dpp_mv<0x128>(x);
    return x16_sum(x);
}
__device__ __forceinline__ float red_sum16(float x) {
    x += dpp_mv<0xB1>(x);
    x += dpp_mv<0x4E>(x);
    x += dpp_mv<0x124>(x);
    x += dpp_mv<0x128>(x);
    return x;
}

// Kernel 1: MFMA conv, M-split: 576 blocks = (i2, cq-half), ~5 blocks/CU.
// Epilogue is LDS-transposed: MFMA frags staged to a [16n][256cq] bf16 tile,
// then read back coalesced and stored as contiguous 512 B runs per (n,i2).
// R11 bug fixed: each readout thread now copies its FULL 32 B (2x uint4);
// R11 copied only 16 B at 32 B stride, leaving half of vout poisoned.
__global__ __launch_bounds__(256)
void conv_v_kernel(const float* __restrict__ x, const float* __restrict__ w,
                   __hip_bfloat16* __restrict__ vout)
{
    __shared__ unsigned short wb[256 * 40];  // [cq_local][p pad40]
    __shared__ unsigned short pb[128 * 40];  // [n][p pad40]
    __shared__ unsigned short st[16 * 264];  // [n_local][cq_local pad264]

    const int bid = blockIdx.x;
    const int i2  = bid >> 1;
    const int mh  = bid & 1;                 // cq half: [mh*256, mh*256+256)
    const int tid = threadIdx.x;

    // zero k=16..31 padding (mfma reads k<32)
    for (int u = tid; u < 256 * 8; u += 256) {
        int r = u >> 3, j = u & 7;
        *(unsigned int*)&wb[r * 40 + 16 + j * 2] = 0;
    }
    for (int u = tid; u < 128 * 8; u += 256) {
        int r = u >> 3, j = u & 7;
        *(unsigned int*)&pb[r * 40 + 16 + j * 2] = 0;
    }
    // stage w[i2][c][p][q] fp32 -> wb[(c_local*16+q)][p] bf16 for c_local 0..15
    #pragma unroll 4
    for (int u = 0; u < 16; ++u) {
        int idx = u * 256 + tid;               // cl*256 + p*16 + q
        int cl = idx >> 8, p = (idx >> 4) & 15, q = idx & 15;
        wb[(cl * 16 + q) * 40 + p] = f2bf(w[(size_t)i2 * 8192 + mh * 4096 + idx]);
    }
    // fused gather: pb[nn][p] from x via reference reshape scramble
    #pragma unroll
    for (int u = 0; u < 8; ++u) {
        int idx = u * 256 + tid;               // nn*16 + p
        int nn = idx >> 4, p = idx & 15;
        int e  = i2 * 16 + p;
        int k2 = e >> 9, c2 = e & 511;
        int f  = k2 * 544 + c2;
        int ci = f / 9, kk = f - ci * 9;
        int bi = nn >> 6, oi = (nn >> 3) & 7, oj = nn & 7;
        int row = 2 * oi + kk / 3 - 1;
        int col = 2 * oj + (kk - (kk / 3) * 3) - 1;
        float val = 0.f;
        if ((unsigned)row < 16u && (unsigned)col < 16u)
            val = x[((bi * 16 + row) * 16 + col) * 544 + ci];
        pb[nn * 40 + p] = f2bf(val);
    }
    __syncthreads();

    const int lane = tid & 63;
    const int wv   = tid >> 6;
    const int l16  = lane & 15;
    const int quad = lane >> 4;
    const int cq0l = wv * 64;                  // local cq base of this wave

    s8v afrag[4], bfrag[8];
    #pragma unroll
    for (int mt = 0; mt < 4; ++mt)
        afrag[mt] = *(const s8v*)&wb[(cq0l + mt * 16 + l16) * 40 + quad * 8];
    #pragma unroll
    for (int nt = 0; nt < 8; ++nt)
        bfrag[nt] = *(const s8v*)&pb[(nt * 16 + l16) * 40 + quad * 8];

    const int srow = tid >> 4;                 // readout row 0..15
    const int schk = tid & 15;                 // readout 16-short chunk
    #pragma unroll
    for (int nt = 0; nt < 8; ++nt) {
        #pragma unroll
        for (int mt = 0; mt < 4; ++mt) {
            f4v acc = {0.f, 0.f, 0.f, 0.f};
            acc = __builtin_amdgcn_mfma_f32_16x16x32_bf16(afrag[mt], bfrag[nt], acc, 0, 0, 0);
            int ccol = cq0l + mt * 16 + quad * 4;   // 0..255 within mh half
            unsigned int lo = f2bf(acc[0]) | ((unsigned int)f2bf(acc[1]) << 16);
            unsigned int hi = f2bf(acc[2]) | ((unsigned int)f2bf(acc[3]) << 16);
            uint2 pk; pk.x = lo; pk.y = hi;
            *(uint2*)&st[l16 * 264 + ccol] = pk;    // row n=l16, 8B aligned
        }
        __syncthreads();
        // coalesced writeback: 16 threads/row x 32 B each = 512 B run
        {
            uint4 d0 = *(const uint4*)&st[srow * 264 + schk * 16];
            uint4 d1 = *(const uint4*)&st[srow * 264 + schk * 16 + 8];
            int nl = nt * 16 + srow;
            unsigned short* dst = (unsigned short*)vout
                + ((size_t)nl * 288 + i2) * 512 + mh * 256 + schk * 16;
            *(uint4*)dst = d0;
            *(uint4*)(dst + 8) = d1;
        }
        __syncthreads();
    }
}

// Kernel 2: one EM sweep (iteration t), grid 768 = (n, h in 0..5). Block =
// 512 threads = 8 waves; each wave does exactly 3 row-pairs (uniform clean
// loop -- the tail/else-prefetch structures that spilled in R3/R5-R7 stay
// banned). Partials to this block's own gpart slot; visibility via stream
// kernel boundaries. No fences, no atomics (R3's AGENT-acquire flushed L2).
__global__ __launch_bounds__(512)
void em_sweep_kernel(const float* __restrict__ x,
                     const unsigned short* __restrict__ v,   // [n][i][cq] bf16
                     const float* __restrict__ beta_u,
                     const float* __restrict__ beta_a,
                     float* __restrict__ gpart,              // [t][n][6][1088]
                     const int t)
{
    __shared__ float fct_s[288];            // a/(a+eps)
    __shared__ float red_s[8 * 64 * 17];    // [wave][lane][s0|s1[8]|s2[8]]
    __shared__ float mu_s[32 * 17];
    __shared__ float i2ss_s[32 * 17];
    __shared__ float kc_s[32];

    const int bid = blockIdx.x;
    const int n   = bid & 127;
    const int h   = bid >> 7;               // 0..5, rows [h*48, h*48+48)
    const int tid = threadIdx.x;
    const int bi = n >> 6, oi = (n >> 3) & 7, oj = n & 7;

    if (tid < 288) {
        int k2 = tid >> 5;
        int c2 = 512 + (tid & 31);
        int f  = k2 * 544 + c2;
        int ci = f / 9;
        int kk = f - ci * 9;
        int row = 2 * oi + kk / 3 - 1;
        int col = 2 * oj + (kk - (kk / 3) * 3) - 1;
        float a = 0.f;
        if ((unsigned)row < 16u && (unsigned)col < 16u)
            a = x[((bi * 16 + row) * 16 + col) * 544 + ci];
        fct_s[tid] = a / (a + EPSV);   // sum_c r*a == a -> rr = softmax * fct
    }

    // finalize previous iteration's stats from all 6 slices (t>0)
    if (t > 0) {
        const int c2 = tid >> 4, q2 = tid & 15;
        const float* pa = gpart + ((size_t)(t - 1) * 128 + n) * 6 * 1088;
        float S1 = 0.f, S2 = 0.f, S0 = 0.f;
        #pragma unroll
        for (int j = 0; j < 6; ++j) {
            S1 += pa[j * 1088 + tid];
            S2 += pa[j * 1088 + 512 + tid];
            S0 += pa[j * 1088 + 1024 + c2];
        }
        float invr = 1.0f / (S0 + EPSV);
        float w0  = S0 * invr;
        float m   = S1 * invr;
        float s2p = S2 * invr;
        float sig = s2p - m * m * (2.0f - w0);   // == sum coeff*(v-mu)^2
        sig = fmaxf(sig + EPSV, 1e-4f);
        float hl = 0.5f * logf(sig);
        mu_s[c2 * 17 + q2]   = m;
        i2ss_s[c2 * 17 + q2] = 1.0f / (2.0f * sig);
        float shl = red_sum16(hl);
        if (q2 == 0) {
            float bu  = beta_u[c2];
            float cs  = (16.0f * bu + shl) * S0;
            float arg = LAMBDAV * (beta_a[c2] - cs);
            float ao  = 1.0f / (1.0f + expf(-arg));
            ao = fminf(fmaxf(ao, 1e-4f), 1.0f - 1e-4f);
            kc_s[c2]  = logf(ao + EPSV) - shl - 8.0f * LN_2PI;
        }
    }
    __syncthreads();

    const unsigned short* vb = v + (size_t)n * 288 * 512;
    const int wv   = tid >> 6;      // wave 0..7
    const int lane = tid & 63;
    const int c    = lane & 31;
    const int qh   = lane >> 5;     // q-half 0/1
    const int qb   = qh * 8;
    const unsigned short* base = vb + c * 16 + qb;

    float mu8[8], is8[8], kcv = 0.f;
    if (t > 0) {
        #pragma unroll
        for (int j = 0; j < 8; ++j) {
            mu8[j] = mu_s[c * 17 + qb + j];
            is8[j] = i2ss_s[c * 17 + qb + j];
        }
        kcv = kc_s[c];
    }

    float s0 = 0.f, s1[8], s2[8];
    #pragma unroll
    for (int j = 0; j < 8; ++j) { s1[j] = 0.f; s2[j] = 0.f; }

    const int kofs = h * 48;         // rows kofs + kp*16 + {wv, wv+8}, kp<3

    // prefetch pair 0
    uint4 ua = *(const uint4*)(base + (size_t)(kofs + 0 + wv) * 512);
    uint4 ub = *(const uint4*)(base + (size_t)(kofs + 8 + wv) * 512);

    #pragma unroll
    for (int kp = 0; kp < 3; ++kp) {
        const int ia = kofs + kp * 16 + wv;
        const int ib = ia + 8;
        uint4 una = ua, unb = ub;
        if (kp < 2) {   // issue next pair before the compute chain
            una = *(const uint4*)(base + (size_t)(ia + 16) * 512);
            unb = *(const uint4*)(base + (size_t)(ia + 24) * 512);
        }
        float va[8], vvb[8];
        va[0] = bflo(ua.x); va[1] = bfhi(ua.x);
        va[2] = bflo(ua.y); va[3] = bfhi(ua.y);
        va[4] = bflo(ua.z); va[5] = bfhi(ua.z);
        va[6] = bflo(ua.w); va[7] = bfhi(ua.w);
        vvb[0] = bflo(ub.x); vvb[1] = bfhi(ub.x);
        vvb[2] = bflo(ub.y); vvb[3] = bfhi(ub.y);
        vvb[4] = bflo(ub.z); vvb[5] = bfhi(ub.z);
        vvb[6] = bflo(ub.w); vvb[7] = bfhi(ub.w);

        float rra, rrb;
        if (t == 0) {
            rra = fct_s[ia] * 0.03125f;
            rrb = fct_s[ib] * 0.03125f;
        } else {
            float pa = 0.f, pb2 = 0.f;
            #pragma unroll
            for (int j = 0; j < 8; ++j) {
                float da = va[j] - mu8[j];
                float db = vvb[j] - mu8[j];
                pa  += da * da * is8[j];
                pb2 += db * db * is8[j];
            }
            pa  = xhalf_sum(pa);      // combine q-halves (xor32, VALU)
            pb2 = xhalf_sum(pb2);
            float acca = kcv - pa;
            float accb = kcv - pb2;
            float mxa = red_max32(acca);
            float mxb = red_max32(accb);
            float ea = __expf(acca - mxa);
            float eb = __expf(accb - mxb);
            float sa = red_sum32(ea);
            float sb = red_sum32(eb);
            rra = (ea / sa) * fct_s[ia];
            rrb = (eb / sb) * fct_s[ib];
        }

        s0 += rra + rrb;
        #pragma unroll
        for (int j = 0; j < 8; ++j) {
            s1[j] += rra * va[j] + rrb * vvb[j];
            s2[j] += rra * va[j] * va[j] + rrb * vvb[j] * vvb[j];
        }
        ua = una; ub = unb;
    }

    // per-wave partials -> LDS (stride 17: 2-way bank alias = free)
    {
        float* dst = &red_s[(wv * 64 + lane) * 17];
        dst[0] = s0;
        #pragma unroll
        for (int j = 0; j < 8; ++j) { dst[1 + j] = s1[j]; dst[9 + j] = s2[j]; }
    }
    __syncthreads();

    // final 8-way reduce -> this block's own gpart slot (plain stores)
    {
        const int c2 = tid >> 4, q2 = tid & 15;
        const int qh2 = q2 >> 3, j2 = q2 & 7;
        float S0 = 0.f, S1 = 0.f, S2 = 0.f;
        #pragma unroll
        for (int wvi = 0; wvi < 8; ++wvi) {
            S0 += red_s[(wvi * 64 + c2) * 17];
            const float* sp = &red_s[(wvi * 64 + qh2 * 32 + c2) * 17];
            S1 += sp[1 + j2];
            S2 += sp[9 + j2];
        }
        float* po = gpart + (((size_t)t * 128 + n) * 6 + h) * 1088;
        po[tid] = S1;
        po[512 + tid] = S2;
        if (q2 == 0) po[1024 + c2] = S0;
    }
}

// Kernel 3: epilogue — finalize t=2 stats, write p_out / a_out / out.
__global__ __launch_bounds__(512)
void em_final_kernel(const float* __restrict__ gpart,
                     const float* __restrict__ beta_u,
                     const float* __restrict__ beta_a,
                     float* __restrict__ out)
{
    __shared__ float aout_s[32];
    const int n   = blockIdx.x;
    const int tid = threadIdx.x;           // 512
    const int c2 = tid >> 4, q2 = tid & 15;

    const float* pa = gpart + ((size_t)2 * 128 + n) * 6 * 1088;
    float S1 = 0.f, S2 = 0.f, S0 = 0.f;
    #pragma unroll
    for (int j = 0; j < 6; ++j) {
        S1 += pa[j * 1088 + tid];
        S2 += pa[j * 1088 + 512 + tid];
        S0 += pa[j * 1088 + 1024 + c2];
    }
    float invr = 1.0f / (S0 + EPSV);
    float w0  = S0 * invr;
    float m   = S1 * invr;
    float s2p = S2 * invr;
    float sig = s2p - m * m * (2.0f - w0);
    sig = fmaxf(sig + EPSV, 1e-4f);
    float hl = 0.5f * logf(sig);
    float shl = red_sum16(hl);
    if (q2 == 0) {
        float bu  = beta_u[c2];
        float cs  = (16.0f * bu + shl) * S0;
        float arg = LAMBDAV * (beta_a[c2] - cs);
        float ao  = 1.0f / (1.0f + expf(-arg));
        ao = fminf(fmaxf(ao, 1e-4f), 1.0f - 1e-4f);
        if (isnan(ao)) ao = 0.5f;
        aout_s[c2] = ao;
    }
    float mu = m;
    if (isnan(mu)) mu = 0.f;
    mu = fminf(fmaxf(mu, -10000.f), 10000.f);
    out[(size_t)n * 512 + tid] = mu;
    out[69632 + (size_t)n * 544 + tid] = mu;
    __syncthreads();
    if (tid < 32) {
        float ao = aout_s[tid];
        out[65536 + n * 32 + tid] = ao;
        out[69632 + n * 544 + 512 + tid] = ao;
    }
}

extern "C" void kernel_launch(void* const* d_in, const int* in_sizes, int n_in,
                              void* d_out, int out_size, void* d_ws, size_t ws_size,
                              hipStream_t stream) {
    const float* x  = (const float*)d_in[0];
    const float* w  = (const float*)d_in[1];
    const float* bu = (const float*)d_in[2];
    const float* ba = (const float*)d_in[3];
    float* out = (float*)d_out;
    __hip_bfloat16* v = (__hip_bfloat16*)d_ws;               // 37.7 MB
    float* gpart = (float*)((char*)d_ws + (40u << 20));      // [3][128][6][1088]

    conv_v_kernel<<<dim3(576), dim3(256), 0, stream>>>(x, w, v);
    em_sweep_kernel<<<dim3(768), dim3(512), 0, stream>>>(
        x, (const unsigned short*)v, bu, ba, gpart, 0);
    em_sweep_kernel<<<dim3(768), dim3(512), 0, stream>>>(
        x, (const unsigned short*)v, bu, ba, gpart, 1);
    em_sweep_kernel<<<dim3(768), dim3(512), 0, stream>>>(
        x, (const unsigned short*)v, bu, ba, gpart, 2);
    em_final_kernel<<<dim3(128), dim3(512), 0, stream>>>(gpart, bu, ba, out);
}